// Round 17
// baseline (1204.712 us; speedup 1.0000x reference)
//
#include <hip/hip_runtime.h>
#include <hip/hip_bf16.h>

typedef __hip_bfloat16 bf16;

#define H 128
#define F3H 384
#define E_RBF 20
#define NLAYER 3

__device__ __forceinline__ float silu_f(float x) { return x / (1.0f + __expf(-x)); }
__device__ __forceinline__ float b2f(bf16 x) { return __bfloat162float(x); }

constexpr float PI_F = 3.14159265358979323846f;
constexpr float CUT = 5.0f;

// ---------------- CSR build ----------------
__global__ __launch_bounds__(256) void csr_hist(
    const int* __restrict__ edge, int* __restrict__ cnt, int nE) {
  int e = blockIdx.x * blockDim.x + threadIdx.x;
  if (e < nE) atomicAdd(&cnt[edge[2 * e]], 1);
}

__global__ __launch_bounds__(256) void csr_scan(
    const int* __restrict__ cnt, int* __restrict__ rowstart, int* __restrict__ cur, int N) {
  __shared__ int part[256];
  int t = threadIdx.x;
  int chunk = (N + 255) / 256;
  int lo = t * chunk; if (lo > N) lo = N;
  int hi = lo + chunk; if (hi > N) hi = N;
  int s = 0;
  for (int i = lo; i < hi; i++) s += cnt[i];
  part[t] = s;
  __syncthreads();
  if (t == 0) {
    int r = 0;
    for (int i = 0; i < 256; i++) { int v = part[i]; part[i] = r; r += v; }
  }
  __syncthreads();
  int r = part[t];
  for (int i = lo; i < hi; i++) { rowstart[i] = r; cur[i] = r; r += cnt[i]; }
}

__global__ __launch_bounds__(256) void csr_fill(
    const int* __restrict__ edge, int* __restrict__ cur, int* __restrict__ elist, int nE) {
  int e = blockIdx.x * blockDim.x + threadIdx.x;
  if (e < nE) {
    int d = edge[2 * e];
    int p = atomicAdd(&cur[d], 1);
    elist[p] = e;
  }
}

// ---------------- edge geometry pack ----------------
__global__ __launch_bounds__(256) void edge_pack(
    const int* __restrict__ elist, const int* __restrict__ edge,
    const float* __restrict__ edist, const float* __restrict__ ediff,
    int* __restrict__ srcs, float* __restrict__ geo, int nE) {
  int j = blockIdx.x * blockDim.x + threadIdx.x;
  if (j >= nE) return;
  int e = elist[j];
  srcs[j] = edge[2 * e + 1];
  float d = edist[e];
  float inv = 1.0f / d;
  float th = d * (PI_F / CUT);
  float s1 = sinf(th), c1 = cosf(th);
  float fc = (d < CUT) ? 0.5f * (c1 + 1.0f) : 0.0f;
  float* g = geo + (size_t)j * 24;
  float twoc = 2.0f * c1;
  float skp = 0.0f, sk = s1;
  #pragma unroll
  for (int k = 0; k < E_RBF; k++) {
    g[k] = sk * inv * fc;
    float nx = twoc * sk - skp;
    skp = sk; sk = nx;
  }
  g[20] = ediff[3 * (size_t)e] * inv;
  g[21] = ediff[3 * (size_t)e + 1] * inv;
  g[22] = ediff[3 * (size_t)e + 2] * inv;
  g[23] = fc;
}

// ---------------- node init ----------------
__global__ __launch_bounds__(H) void node_init(
    const int* __restrict__ z, const float* __restrict__ embed,
    float* __restrict__ ns, int N) {
  int i = blockIdx.x;
  int h = threadIdx.x;
  ns[(size_t)i * H + h] = embed[(size_t)z[i] * H + h];
}

__device__ __forceinline__ void store_bf16x4(bf16* p, float4 v) {
  union { bf16 b[4]; ushort4 u; } t;
  t.b[0] = __float2bfloat16(v.x);
  t.b[1] = __float2bfloat16(v.y);
  t.b[2] = __float2bfloat16(v.z);
  t.b[3] = __float2bfloat16(v.w);
  *(ushort4*)p = t.u;
}

// ======== fused scalar MLP: 32 rows / 512 threads / dbuf panels ========
// 512 thr = 8 waves/CU at grid 313 (was 4). waves_per_eu(1,2): 256-VGPR budget
// so the 2x4 per-thread tile + epilogue never spills (R14 lesson).
__global__ __launch_bounds__(512) __attribute__((amdgpu_waves_per_eu(1, 2)))
void scalar_mlp_fused(const float* __restrict__ A,
                      const float* __restrict__ W1, const float* __restrict__ b1,
                      const float* __restrict__ W2, const float* __restrict__ b2,
                      bf16* __restrict__ C, int M) {
  __shared__ float s_a[32][132];
  __shared__ float s_w[2][16][128];
  int i0 = blockIdx.x * 32;
  int tid = threadIdx.x;
  for (int idx = tid; idx < 32 * 128; idx += 512) {
    int r = idx >> 7, k = idx & 127;
    int gr = i0 + r;
    s_a[r][k] = (gr < M) ? A[(size_t)gr * H + k] : 0.0f;
  }
  int mq = tid >> 5, hq = tid & 31;       // mq 0..15 -> 2 rows each
  int col = 4 * hq;
  int srow = tid >> 5, scol0 = (tid & 31) << 2;   // one f4/thread staging
  *(float4*)&s_w[0][srow][scol0] = *(const float4*)&W1[(size_t)srow * H + scol0];
  float acc[2][4] = {};
  for (int p = 0; p < 8; p++) {
    __syncthreads();
    if (p + 1 < 8)
      *(float4*)&s_w[(p + 1) & 1][srow][scol0] =
          *(const float4*)&W1[(size_t)((p + 1) * 16 + srow) * H + scol0];
    int kp = p * 16;
    #pragma unroll
    for (int kq = 0; kq < 4; kq++) {
      float4 av[2];
      #pragma unroll
      for (int i = 0; i < 2; i++) av[i] = *(const float4*)&s_a[2 * mq + i][kp + 4 * kq];
      #pragma unroll
      for (int k2 = 0; k2 < 4; k2++) {
        float4 w4 = *(const float4*)&s_w[p & 1][4 * kq + k2][4 * hq];
        #pragma unroll
        for (int i = 0; i < 2; i++) {
          float a = ((const float*)&av[i])[k2];
          acc[i][0] += a * w4.x; acc[i][1] += a * w4.y;
          acc[i][2] += a * w4.z; acc[i][3] += a * w4.w;
        }
      }
    }
  }
  float4 b14 = *(const float4*)&b1[col];
  __syncthreads();
  #pragma unroll
  for (int i = 0; i < 2; i++) {
    float4 o;
    o.x = silu_f(acc[i][0] + b14.x); o.y = silu_f(acc[i][1] + b14.y);
    o.z = silu_f(acc[i][2] + b14.z); o.w = silu_f(acc[i][3] + b14.w);
    *(float4*)&s_a[2 * mq + i][col] = o;
  }
  *(float4*)&s_w[0][srow][scol0] = *(const float4*)&W2[(size_t)srow * F3H + scol0];
  float a2[2][4] = {};
  for (int p = 0; p < 24; p++) {
    __syncthreads();
    if (p + 1 < 24) {
      int cpn = (p + 1) >> 3, kpn = ((p + 1) & 7) * 16;
      *(float4*)&s_w[(p + 1) & 1][srow][scol0] =
          *(const float4*)&W2[(size_t)(kpn + srow) * F3H + cpn * 128 + scol0];
    }
    int kp = (p & 7) * 16;
    #pragma unroll
    for (int kq = 0; kq < 4; kq++) {
      float4 av[2];
      #pragma unroll
      for (int i = 0; i < 2; i++) av[i] = *(const float4*)&s_a[2 * mq + i][kp + 4 * kq];
      #pragma unroll
      for (int k2 = 0; k2 < 4; k2++) {
        float4 w4 = *(const float4*)&s_w[p & 1][4 * kq + k2][4 * hq];
        #pragma unroll
        for (int i = 0; i < 2; i++) {
          float a = ((const float*)&av[i])[k2];
          a2[i][0] += a * w4.x; a2[i][1] += a * w4.y;
          a2[i][2] += a * w4.z; a2[i][3] += a * w4.w;
        }
      }
    }
    if ((p & 7) == 7) {
      int cp = p >> 3;
      float4 b24 = *(const float4*)&b2[cp * 128 + col];
      #pragma unroll
      for (int i = 0; i < 2; i++) {
        int gr = i0 + 2 * mq + i;
        if (gr < M) {
          float4 o;
          o.x = a2[i][0] + b24.x; o.y = a2[i][1] + b24.y;
          o.z = a2[i][2] + b24.z; o.w = a2[i][3] + b24.w;
          store_bf16x4(&C[(size_t)gr * F3H + cp * 128 + col], o);
        }
        a2[i][0] = 0.0f; a2[i][1] = 0.0f; a2[i][2] = 0.0f; a2[i][3] = 0.0f;
      }
    }
  }
}

// ---------------- dual GEMM Uv/Vv: 32 rows / 512 threads / dbuf ----------------
__global__ __launch_bounds__(512) __attribute__((amdgpu_waves_per_eu(1, 2)))
void gemm_uv(const float* __restrict__ A,
             const float* __restrict__ Wu, const float* __restrict__ bu,
             const float* __restrict__ Wv, const float* __restrict__ bv,
             float* __restrict__ Cu, float* __restrict__ Cv, int M) {
  __shared__ float s_a[32][132];
  __shared__ float s_wu[2][16][128];
  __shared__ float s_wv[2][16][128];
  int i0 = blockIdx.x * 32;
  int tid = threadIdx.x;
  for (int idx = tid; idx < 32 * 128; idx += 512) {
    int r = idx >> 7, k = idx & 127;
    int gr = i0 + r;
    s_a[r][k] = (gr < M) ? A[(size_t)gr * H + k] : 0.0f;
  }
  int mq = tid >> 5, hq = tid & 31;
  int col = 4 * hq;
  int srow = tid >> 5, scol0 = (tid & 31) << 2;
  *(float4*)&s_wu[0][srow][scol0] = *(const float4*)&Wu[(size_t)srow * H + scol0];
  *(float4*)&s_wv[0][srow][scol0] = *(const float4*)&Wv[(size_t)srow * H + scol0];
  float au[2][4] = {}, av_[2][4] = {};
  for (int p = 0; p < 8; p++) {
    __syncthreads();
    if (p + 1 < 8) {
      *(float4*)&s_wu[(p + 1) & 1][srow][scol0] =
          *(const float4*)&Wu[(size_t)((p + 1) * 16 + srow) * H + scol0];
      *(float4*)&s_wv[(p + 1) & 1][srow][scol0] =
          *(const float4*)&Wv[(size_t)((p + 1) * 16 + srow) * H + scol0];
    }
    int kp = p * 16;
    #pragma unroll
    for (int kq = 0; kq < 4; kq++) {
      float4 aa[2];
      #pragma unroll
      for (int i = 0; i < 2; i++) aa[i] = *(const float4*)&s_a[2 * mq + i][kp + 4 * kq];
      #pragma unroll
      for (int k2 = 0; k2 < 4; k2++) {
        float4 wu4 = *(const float4*)&s_wu[p & 1][4 * kq + k2][4 * hq];
        float4 wv4 = *(const float4*)&s_wv[p & 1][4 * kq + k2][4 * hq];
        #pragma unroll
        for (int i = 0; i < 2; i++) {
          float a = ((const float*)&aa[i])[k2];
          au[i][0] += a * wu4.x; au[i][1] += a * wu4.y;
          au[i][2] += a * wu4.z; au[i][3] += a * wu4.w;
          av_[i][0] += a * wv4.x; av_[i][1] += a * wv4.y;
          av_[i][2] += a * wv4.z; av_[i][3] += a * wv4.w;
        }
      }
    }
  }
  float4 bu4 = *(const float4*)&bu[col];
  float4 bv4 = *(const float4*)&bv[col];
  #pragma unroll
  for (int i = 0; i < 2; i++) {
    int gr = i0 + 2 * mq + i;
    if (gr < M) {
      float4 ou, ov;
      ou.x = au[i][0] + bu4.x; ou.y = au[i][1] + bu4.y; ou.z = au[i][2] + bu4.z; ou.w = au[i][3] + bu4.w;
      ov.x = av_[i][0] + bv4.x; ov.y = av_[i][1] + bv4.y; ov.z = av_[i][2] + bv4.z; ov.w = av_[i][3] + bv4.w;
      *(float4*)&Cu[(size_t)gr * H + col] = ou;
      *(float4*)&Cv[(size_t)gr * H + col] = ov;
    }
  }
}

// ======== fused update MLP + epilogue: 32 rows / 512 threads / dbuf ========
__global__ __launch_bounds__(512) __attribute__((amdgpu_waves_per_eu(1, 2)))
void update_fused(float* __restrict__ ns, float* __restrict__ nv,
                  bf16* __restrict__ nvb16,
                  const float* __restrict__ Uv, const float* __restrict__ Vv,
                  const float* __restrict__ W1, const float* __restrict__ b1,
                  const float* __restrict__ W2, const float* __restrict__ b2,
                  int M) {
  __shared__ float s_a[32][260];
  __shared__ float s_w[2][16][128];
  int i0 = blockIdx.x * 32;
  int tid = threadIdx.x;
  for (int idx = tid; idx < 32 * 256; idx += 512) {
    int r = idx >> 8, k = idx & 255;
    int gr = i0 + r;
    float val = 0.0f;
    if (gr < M) {
      if (k < H) {
        float v0 = Vv[(size_t)(3 * gr + 0) * H + k];
        float v1 = Vv[(size_t)(3 * gr + 1) * H + k];
        float v2 = Vv[(size_t)(3 * gr + 2) * H + k];
        val = sqrtf(v0 * v0 + v1 * v1 + v2 * v2);
      } else {
        val = ns[(size_t)gr * H + (k - H)];
      }
    }
    s_a[r][k] = val;
  }
  int mq = tid >> 5, hq = tid & 31;
  int col = 4 * hq;
  int srow = tid >> 5, scol0 = (tid & 31) << 2;
  *(float4*)&s_w[0][srow][scol0] = *(const float4*)&W1[(size_t)srow * H + scol0];
  float acc[2][4] = {};
  for (int p = 0; p < 16; p++) {
    __syncthreads();
    if (p + 1 < 16)
      *(float4*)&s_w[(p + 1) & 1][srow][scol0] =
          *(const float4*)&W1[(size_t)((p + 1) * 16 + srow) * H + scol0];
    int kp = p * 16;
    #pragma unroll
    for (int kq = 0; kq < 4; kq++) {
      float4 aa[2];
      #pragma unroll
      for (int i = 0; i < 2; i++) aa[i] = *(const float4*)&s_a[2 * mq + i][kp + 4 * kq];
      #pragma unroll
      for (int k2 = 0; k2 < 4; k2++) {
        float4 w4 = *(const float4*)&s_w[p & 1][4 * kq + k2][4 * hq];
        #pragma unroll
        for (int i = 0; i < 2; i++) {
          float a = ((const float*)&aa[i])[k2];
          acc[i][0] += a * w4.x; acc[i][1] += a * w4.y;
          acc[i][2] += a * w4.z; acc[i][3] += a * w4.w;
        }
      }
    }
  }
  float4 b14 = *(const float4*)&b1[col];
  __syncthreads();
  #pragma unroll
  for (int i = 0; i < 2; i++) {
    float4 o;
    o.x = silu_f(acc[i][0] + b14.x); o.y = silu_f(acc[i][1] + b14.y);
    o.z = silu_f(acc[i][2] + b14.z); o.w = silu_f(acc[i][3] + b14.w);
    *(float4*)&s_a[2 * mq + i][col] = o;
  }
  *(float4*)&s_w[0][srow][scol0] = *(const float4*)&W2[(size_t)srow * F3H + scol0];
  float g_av[2][4], g_as[2][4], g_ss[2][4];
  float a2[2][4] = {};
  for (int p = 0; p < 24; p++) {
    __syncthreads();
    if (p + 1 < 24) {
      int cpn = (p + 1) >> 3, kpn = ((p + 1) & 7) * 16;
      *(float4*)&s_w[(p + 1) & 1][srow][scol0] =
          *(const float4*)&W2[(size_t)(kpn + srow) * F3H + cpn * 128 + scol0];
    }
    int kp = (p & 7) * 16;
    #pragma unroll
    for (int kq = 0; kq < 4; kq++) {
      float4 aa[2];
      #pragma unroll
      for (int i = 0; i < 2; i++) aa[i] = *(const float4*)&s_a[2 * mq + i][kp + 4 * kq];
      #pragma unroll
      for (int k2 = 0; k2 < 4; k2++) {
        float4 w4 = *(const float4*)&s_w[p & 1][4 * kq + k2][4 * hq];
        #pragma unroll
        for (int i = 0; i < 2; i++) {
          float a = ((const float*)&aa[i])[k2];
          a2[i][0] += a * w4.x; a2[i][1] += a * w4.y;
          a2[i][2] += a * w4.z; a2[i][3] += a * w4.w;
        }
      }
    }
    if ((p & 7) == 7) {
      int cp = p >> 3;
      float4 b24 = *(const float4*)&b2[cp * 128 + col];
      #pragma unroll
      for (int i = 0; i < 2; i++) {
        float v0 = a2[i][0] + b24.x, v1 = a2[i][1] + b24.y;
        float v2 = a2[i][2] + b24.z, v3 = a2[i][3] + b24.w;
        if (cp == 0) { g_av[i][0] = v0; g_av[i][1] = v1; g_av[i][2] = v2; g_av[i][3] = v3; }
        if (cp == 1) { g_as[i][0] = v0; g_as[i][1] = v1; g_as[i][2] = v2; g_as[i][3] = v3; }
        if (cp == 2) { g_ss[i][0] = v0; g_ss[i][1] = v1; g_ss[i][2] = v2; g_ss[i][3] = v3; }
        a2[i][0] = 0.0f; a2[i][1] = 0.0f; a2[i][2] = 0.0f; a2[i][3] = 0.0f;
      }
    }
  }
  #pragma unroll
  for (int i = 0; i < 2; i++) {
    int gr = i0 + 2 * mq + i;
    if (gr < M) {
      float4 u0 = *(const float4*)&Uv[(size_t)(3 * gr + 0) * H + col];
      float4 u1 = *(const float4*)&Uv[(size_t)(3 * gr + 1) * H + col];
      float4 u2 = *(const float4*)&Uv[(size_t)(3 * gr + 2) * H + col];
      float4 v0 = *(const float4*)&Vv[(size_t)(3 * gr + 0) * H + col];
      float4 v1 = *(const float4*)&Vv[(size_t)(3 * gr + 1) * H + col];
      float4 v2 = *(const float4*)&Vv[(size_t)(3 * gr + 2) * H + col];
      float4 dot;
      dot.x = u0.x * v0.x + u1.x * v1.x + u2.x * v2.x;
      dot.y = u0.y * v0.y + u1.y * v1.y + u2.y * v2.y;
      dot.z = u0.z * v0.z + u1.z * v1.z + u2.z * v2.z;
      dot.w = u0.w * v0.w + u1.w * v1.w + u2.w * v2.w;
      float4 nsv = *(float4*)&ns[(size_t)gr * H + col];
      nsv.x += g_as[i][0] * dot.x + g_ss[i][0];
      nsv.y += g_as[i][1] * dot.y + g_ss[i][1];
      nsv.z += g_as[i][2] * dot.z + g_ss[i][2];
      nsv.w += g_as[i][3] * dot.w + g_ss[i][3];
      *(float4*)&ns[(size_t)gr * H + col] = nsv;
      float4 n0 = *(float4*)&nv[(size_t)(3 * gr + 0) * H + col];
      float4 n1 = *(float4*)&nv[(size_t)(3 * gr + 1) * H + col];
      float4 n2 = *(float4*)&nv[(size_t)(3 * gr + 2) * H + col];
      n0.x += g_av[i][0] * u0.x; n0.y += g_av[i][1] * u0.y; n0.z += g_av[i][2] * u0.z; n0.w += g_av[i][3] * u0.w;
      n1.x += g_av[i][0] * u1.x; n1.y += g_av[i][1] * u1.y; n1.z += g_av[i][2] * u1.z; n1.w += g_av[i][3] * u1.w;
      n2.x += g_av[i][0] * u2.x; n2.y += g_av[i][1] * u2.y; n2.z += g_av[i][2] * u2.z; n2.w += g_av[i][3] * u2.w;
      *(float4*)&nv[(size_t)(3 * gr + 0) * H + col] = n0;
      *(float4*)&nv[(size_t)(3 * gr + 1) * H + col] = n1;
      *(float4*)&nv[(size_t)(3 * gr + 2) * H + col] = n2;
      store_bf16x4(&nvb16[((size_t)gr * 3 + 0) * H + col], n0);
      store_bf16x4(&nvb16[((size_t)gr * 3 + 1) * H + col], n1);
      store_bf16x4(&nvb16[((size_t)gr * 3 + 2) * H + col], n2);
    }
  }
}

// ======== fused readout: 32 rows / 512 threads / dbuf ========
__global__ __launch_bounds__(512) __attribute__((amdgpu_waves_per_eu(1, 2)))
void readout_fused(const float* __restrict__ A,
                   const float* __restrict__ W1, const float* __restrict__ b1,
                   const float* __restrict__ W2, const float* __restrict__ b2,
                   float* __restrict__ C, int M) {
  __shared__ float s_a[32][132];
  __shared__ float s_w[2][16][128];
  int i0 = blockIdx.x * 32;
  int tid = threadIdx.x;
  for (int idx = tid; idx < 32 * 128; idx += 512) {
    int r = idx >> 7, k = idx & 127;
    int gr = i0 + r;
    s_a[r][k] = (gr < M) ? A[(size_t)gr * H + k] : 0.0f;
  }
  int mq = tid >> 5, hq = tid & 31;
  int col = 4 * hq;
  int srow = tid >> 5, scol0 = (tid & 31) << 2;
  *(float4*)&s_w[0][srow][scol0] = *(const float4*)&W1[(size_t)srow * H + scol0];
  float acc[2][4] = {};
  for (int p = 0; p < 8; p++) {
    __syncthreads();
    if (p + 1 < 8)
      *(float4*)&s_w[(p + 1) & 1][srow][scol0] =
          *(const float4*)&W1[(size_t)((p + 1) * 16 + srow) * H + scol0];
    int kp = p * 16;
    #pragma unroll
    for (int kq = 0; kq < 4; kq++) {
      float4 av[2];
      #pragma unroll
      for (int i = 0; i < 2; i++) av[i] = *(const float4*)&s_a[2 * mq + i][kp + 4 * kq];
      #pragma unroll
      for (int k2 = 0; k2 < 4; k2++) {
        float4 w4 = *(const float4*)&s_w[p & 1][4 * kq + k2][4 * hq];
        #pragma unroll
        for (int i = 0; i < 2; i++) {
          float a = ((const float*)&av[i])[k2];
          acc[i][0] += a * w4.x; acc[i][1] += a * w4.y;
          acc[i][2] += a * w4.z; acc[i][3] += a * w4.w;
        }
      }
    }
  }
  float4 b14 = *(const float4*)&b1[col];
  __syncthreads();
  #pragma unroll
  for (int i = 0; i < 2; i++) {
    float4 o;
    o.x = silu_f(acc[i][0] + b14.x); o.y = silu_f(acc[i][1] + b14.y);
    o.z = silu_f(acc[i][2] + b14.z); o.w = silu_f(acc[i][3] + b14.w);
    *(float4*)&s_a[2 * mq + i][col] = o;
  }
  *(float4*)&s_w[0][srow][scol0] = *(const float4*)&W2[(size_t)srow * H + scol0];
  float a2[2][4] = {};
  for (int p = 0; p < 8; p++) {
    __syncthreads();
    if (p + 1 < 8)
      *(float4*)&s_w[(p + 1) & 1][srow][scol0] =
          *(const float4*)&W2[(size_t)((p + 1) * 16 + srow) * H + scol0];
    int kp = p * 16;
    #pragma unroll
    for (int kq = 0; kq < 4; kq++) {
      float4 av[2];
      #pragma unroll
      for (int i = 0; i < 2; i++) av[i] = *(const float4*)&s_a[2 * mq + i][kp + 4 * kq];
      #pragma unroll
      for (int k2 = 0; k2 < 4; k2++) {
        float4 w4 = *(const float4*)&s_w[p & 1][4 * kq + k2][4 * hq];
        #pragma unroll
        for (int i = 0; i < 2; i++) {
          float a = ((const float*)&av[i])[k2];
          a2[i][0] += a * w4.x; a2[i][1] += a * w4.y;
          a2[i][2] += a * w4.z; a2[i][3] += a * w4.w;
        }
      }
    }
  }
  float4 b24 = *(const float4*)&b2[col];
  #pragma unroll
  for (int i = 0; i < 2; i++) {
    int gr = i0 + 2 * mq + i;
    if (gr < M) {
      float4 o;
      o.x = a2[i][0] + b24.x; o.y = a2[i][1] + b24.y;
      o.z = a2[i][2] + b24.z; o.w = a2[i][3] + b24.w;
      *(float4*)&C[(size_t)gr * H + col] = o;
    }
  }
}

// ---------------- message: bf16 gathers; fp32 state ----------------
template<bool HASNV>
__global__ __launch_bounds__(128, 4) void message3(
    const int* __restrict__ srcs, const int* __restrict__ rowstart,
    const int* __restrict__ cnt, const float* __restrict__ geo,
    const float* __restrict__ Wf, const float* __restrict__ bfb,
    const bf16* __restrict__ so, const bf16* __restrict__ nvb16,
    const float* __restrict__ nvA,
    float* __restrict__ ns, float* __restrict__ nvB, int N) {
  int i = blockIdx.x;
  int h = threadIdx.x;

  float wf0[E_RBF], wf1[E_RBF], wf2[E_RBF];
  #pragma unroll
  for (int k = 0; k < E_RBF; k++) {
    wf0[k] = Wf[k * F3H + h];
    wf1[k] = Wf[k * F3H + H + h];
    wf2[k] = Wf[k * F3H + 2 * H + h];
  }
  float bb0 = bfb[h], bb1 = bfb[H + h], bb2 = bfb[2 * H + h];

  float accs = 0.0f, a0 = 0.0f, a1 = 0.0f, a2 = 0.0f;
  int jlo = rowstart[i], jhi = jlo + cnt[i];
  for (int j = jlo; j < jhi; j++) {
    int src = srcs[j];
    const float* g = geo + (size_t)j * 24;
    float gg[24];
    #pragma unroll
    for (int q = 0; q < 6; q++) *(float4*)&gg[4 * q] = *(const float4*)&g[4 * q];

    float fc = gg[23];
    float f0 = bb0 * fc, f1 = bb1 * fc, f2 = bb2 * fc;
    #pragma unroll
    for (int k = 0; k < E_RBF; k++) {
      float rk = gg[k];
      f0 += rk * wf0[k];
      f1 += rk * wf1[k];
      f2 += rk * wf2[k];
    }
    float u0 = gg[20], u1 = gg[21], u2 = gg[22];

    const bf16* sop = so + (size_t)src * F3H;
    float gsv = f0 * b2f(sop[h]);
    float gev = f1 * b2f(sop[H + h]);
    accs += f2 * b2f(sop[2 * H + h]);

    if (HASNV) {
      const bf16* nvp = nvb16 + (size_t)src * F3H;
      a0 += b2f(nvp[h])         * gsv + gev * u0;
      a1 += b2f(nvp[H + h])     * gsv + gev * u1;
      a2 += b2f(nvp[2 * H + h]) * gsv + gev * u2;
    } else {
      a0 += gev * u0;
      a1 += gev * u1;
      a2 += gev * u2;
    }
  }

  ns[(size_t)i * H + h] += accs;
  if (HASNV) {
    const float* nvi = nvA + (size_t)i * F3H;
    nvB[(size_t)i * F3H + h]         = nvi[h] + a0;
    nvB[(size_t)i * F3H + H + h]     = nvi[H + h] + a1;
    nvB[(size_t)i * F3H + 2 * H + h] = nvi[2 * H + h] + a2;
  } else {
    nvB[(size_t)i * F3H + h]         = a0;
    nvB[(size_t)i * F3H + H + h]     = a1;
    nvB[(size_t)i * F3H + 2 * H + h] = a2;
  }
}

extern "C" void kernel_launch(void* const* d_in, const int* in_sizes, int n_in,
                              void* d_out, int out_size, void* d_ws, size_t ws_size,
                              hipStream_t stream) {
  const int*   z     = (const int*)d_in[0];
  const int*   edge  = (const int*)d_in[1];
  const float* ediff = (const float*)d_in[2];
  const float* edist = (const float*)d_in[3];
  const float* embed = (const float*)d_in[4];
  const float* mfw   = (const float*)d_in[5];
  const float* mfb   = (const float*)d_in[6];
  const float* mw1   = (const float*)d_in[7];
  const float* mb1   = (const float*)d_in[8];
  const float* mw2   = (const float*)d_in[9];
  const float* mb2   = (const float*)d_in[10];
  const float* uUw   = (const float*)d_in[11];
  const float* uUb   = (const float*)d_in[12];
  const float* uVw   = (const float*)d_in[13];
  const float* uVb   = (const float*)d_in[14];
  const float* uw1   = (const float*)d_in[15];
  const float* ub1   = (const float*)d_in[16];
  const float* uw2   = (const float*)d_in[17];
  const float* ub2   = (const float*)d_in[18];
  const float* rw1   = (const float*)d_in[19];
  const float* rb1   = (const float*)d_in[20];
  const float* rw2   = (const float*)d_in[21];
  const float* rb2   = (const float*)d_in[22];

  const int N  = in_sizes[0];   // 10000
  const int nE = in_sizes[3];   // 160000

  float* ws = (float*)d_ws;
  size_t off = 0;
  float* ns    = ws + off; off += (size_t)N * H;
  float* nvA   = ws + off; off += (size_t)N * F3H;
  float* nvB   = ws + off; off += (size_t)N * F3H;
  float* Vv    = ws + off; off += (size_t)N * F3H;
  float* geo   = ws + off; off += (size_t)nE * 24;
  bf16* so     = (bf16*)(ws + off); off += (size_t)N * F3H / 2;
  bf16* nvb16  = (bf16*)(ws + off); off += (size_t)N * F3H / 2;
  int* srcs     = (int*)(ws + off); off += nE;
  int* cnt      = (int*)(ws + off); off += N;
  int* rowstart = (int*)(ws + off); off += N;
  int* cur      = (int*)(ws + off); off += N;
  int* elist    = (int*)(ws + off); off += nE;

  const int tilesN  = (N + 31) / 32;        // 313
  const int tiles3N = (3 * N + 31) / 32;    // 938

  (void)hipMemsetAsync(cnt, 0, (size_t)N * sizeof(int), stream);
  csr_hist<<<(nE + 255) / 256, 256, 0, stream>>>(edge, cnt, nE);
  csr_scan<<<1, 256, 0, stream>>>(cnt, rowstart, cur, N);
  csr_fill<<<(nE + 255) / 256, 256, 0, stream>>>(edge, cur, elist, nE);
  edge_pack<<<(nE + 255) / 256, 256, 0, stream>>>(elist, edge, edist, ediff, srcs, geo, nE);

  node_init<<<N, H, 0, stream>>>(z, embed, ns, N);

  float* nv_cur = nvA;
  float* nv_nxt = nvB;
  for (int l = 0; l < NLAYER; l++) {
    scalar_mlp_fused<<<tilesN, 512, 0, stream>>>(
        ns, mw1 + (size_t)l * H * H, mb1 + (size_t)l * H,
        mw2 + (size_t)l * H * F3H, mb2 + (size_t)l * F3H, so, N);

    if (l == 0)
      message3<false><<<N, H, 0, stream>>>(srcs, rowstart, cnt, geo,
                                           mfw + (size_t)l * E_RBF * F3H, mfb + (size_t)l * F3H,
                                           so, nvb16, nv_cur, ns, nv_nxt, N);
    else
      message3<true><<<N, H, 0, stream>>>(srcs, rowstart, cnt, geo,
                                          mfw + (size_t)l * E_RBF * F3H, mfb + (size_t)l * F3H,
                                          so, nvb16, nv_cur, ns, nv_nxt, N);

    float* Uv = nv_cur;  // dead after message3 — reuse as Uv scratch
    gemm_uv<<<tiles3N, 512, 0, stream>>>(
        nv_nxt,
        uUw + (size_t)l * H * H, uUb + (size_t)l * H,
        uVw + (size_t)l * H * H, uVb + (size_t)l * H,
        Uv, Vv, 3 * N);

    update_fused<<<tilesN, 512, 0, stream>>>(
        ns, nv_nxt, nvb16, Uv, Vv,
        uw1 + (size_t)l * 2 * H * H, ub1 + (size_t)l * H,
        uw2 + (size_t)l * H * F3H, ub2 + (size_t)l * F3H, N);

    float* t = nv_cur; nv_cur = nv_nxt; nv_nxt = t;
  }

  readout_fused<<<tilesN, 512, 0, stream>>>(ns, rw1, rb1, rw2, rb2, (float*)d_out, N);
}

// Round 18
// 714.224 us; speedup vs baseline: 1.6867x; 1.6867x over previous
//
#include <hip/hip_runtime.h>
#include <hip/hip_bf16.h>

typedef __hip_bfloat16 bf16;
typedef __attribute__((ext_vector_type(8))) short bf16x8;
typedef __attribute__((ext_vector_type(4))) float f32x4;

#define H 128
#define F3H 384
#define E_RBF 20
#define NLAYER 3

__device__ __forceinline__ float silu_f(float x) { return x / (1.0f + __expf(-x)); }
__device__ __forceinline__ float b2f(bf16 x) { return __bfloat162float(x); }

constexpr float PI_F = 3.14159265358979323846f;
constexpr float CUT = 5.0f;

// ---------------- CSR build ----------------
__global__ __launch_bounds__(256) void csr_hist(
    const int* __restrict__ edge, int* __restrict__ cnt, int nE) {
  int e = blockIdx.x * blockDim.x + threadIdx.x;
  if (e < nE) atomicAdd(&cnt[edge[2 * e]], 1);
}

__global__ __launch_bounds__(256) void csr_scan(
    const int* __restrict__ cnt, int* __restrict__ rowstart, int* __restrict__ cur, int N) {
  __shared__ int part[256];
  int t = threadIdx.x;
  int chunk = (N + 255) / 256;
  int lo = t * chunk; if (lo > N) lo = N;
  int hi = lo + chunk; if (hi > N) hi = N;
  int s = 0;
  for (int i = lo; i < hi; i++) s += cnt[i];
  part[t] = s;
  __syncthreads();
  if (t == 0) {
    int r = 0;
    for (int i = 0; i < 256; i++) { int v = part[i]; part[i] = r; r += v; }
  }
  __syncthreads();
  int r = part[t];
  for (int i = lo; i < hi; i++) { rowstart[i] = r; cur[i] = r; r += cnt[i]; }
}

__global__ __launch_bounds__(256) void csr_fill(
    const int* __restrict__ edge, int* __restrict__ cur, int* __restrict__ elist, int nE) {
  int e = blockIdx.x * blockDim.x + threadIdx.x;
  if (e < nE) {
    int d = edge[2 * e];
    int p = atomicAdd(&cur[d], 1);
    elist[p] = e;
  }
}

// ---------------- edge geometry pack ----------------
__global__ __launch_bounds__(256) void edge_pack(
    const int* __restrict__ elist, const int* __restrict__ edge,
    const float* __restrict__ edist, const float* __restrict__ ediff,
    int* __restrict__ srcs, float* __restrict__ geo, int nE) {
  int j = blockIdx.x * blockDim.x + threadIdx.x;
  if (j >= nE) return;
  int e = elist[j];
  srcs[j] = edge[2 * e + 1];
  float d = edist[e];
  float inv = 1.0f / d;
  float th = d * (PI_F / CUT);
  float s1 = sinf(th), c1 = cosf(th);
  float fc = (d < CUT) ? 0.5f * (c1 + 1.0f) : 0.0f;
  float* g = geo + (size_t)j * 24;
  float twoc = 2.0f * c1;
  float skp = 0.0f, sk = s1;
  #pragma unroll
  for (int k = 0; k < E_RBF; k++) {
    g[k] = sk * inv * fc;
    float nx = twoc * sk - skp;
    skp = sk; sk = nx;
  }
  g[20] = ediff[3 * (size_t)e] * inv;
  g[21] = ediff[3 * (size_t)e + 1] * inv;
  g[22] = ediff[3 * (size_t)e + 2] * inv;
  g[23] = fc;
}

// ---------------- node init ----------------
__global__ __launch_bounds__(H) void node_init(
    const int* __restrict__ z, const float* __restrict__ embed,
    float* __restrict__ ns, int N) {
  int i = blockIdx.x;
  int h = threadIdx.x;
  ns[(size_t)i * H + h] = embed[(size_t)z[i] * H + h];
}

__device__ __forceinline__ void store_bf16x4(bf16* p, float4 v) {
  union { bf16 b[4]; ushort4 u; } t;
  t.b[0] = __float2bfloat16(v.x);
  t.b[1] = __float2bfloat16(v.y);
  t.b[2] = __float2bfloat16(v.z);
  t.b[3] = __float2bfloat16(v.w);
  *(ushort4*)p = t.u;
}

// ---------------- pack U/V weights into MFMA B-fragment layout ----------------
// B-frag (16x16x32 bf16): lane holds B[k=quad*8+j][n=lane&15], j=0..7.
// packed[(l*2+mat)*16384 + ((kb*8+c)*64 + lane)*8 + j]
__global__ __launch_bounds__(256) void pack_w(
    const float* __restrict__ Wu, const float* __restrict__ Wv,
    bf16* __restrict__ wp) {
  int t = blockIdx.x * blockDim.x + threadIdx.x;   // 12288 total
  if (t >= 3 * 2 * 4 * 8 * 64) return;
  int lane = t & 63;
  int c    = (t >> 6) & 7;
  int kb   = (t >> 9) & 3;
  int mat  = (t >> 11) & 1;
  int l    = t >> 12;
  const float* src = (mat ? Wv : Wu) + (size_t)l * H * H;
  bf16* dst = wp + ((size_t)(l * 2 + mat) * 16384) + (((kb * 8 + c) * 64 + lane) * 8);
  int quad = lane >> 4;
  int n = c * 16 + (lane & 15);
  #pragma unroll
  for (int j = 0; j < 8; j++) {
    int k = kb * 32 + quad * 8 + j;
    dst[j] = __float2bfloat16(src[(size_t)k * H + n]);
  }
}

// ---------------- MFMA dual GEMM: Uv/Vv from bf16 A + packed bf16 W ----------------
// No LDS, no barriers. Wave = 16 rows x 128 cols; block = 4 waves = 64 rows.
__global__ __launch_bounds__(256) void gemm_uv_mfma(
    const bf16* __restrict__ A,      // [M][128] bf16 (nvmsg16)
    const bf16* __restrict__ Wp,     // packed this layer: [2][4][8][64][8]
    const float* __restrict__ bu, const float* __restrict__ bv,
    float* __restrict__ Cu, float* __restrict__ Cv, int M) {
  int wave = threadIdx.x >> 6;
  int lane = threadIdx.x & 63;
  int r0 = blockIdx.x * 64 + wave * 16;
  int quad = lane >> 4;
  int nn = lane & 15;
  int arow = r0 + nn;                 // A m-index = lane&15
  if (arow >= M) arow = M - 1;        // clamp; stores guarded below
  f32x4 accu[8] = {};
  f32x4 accv[8] = {};
  for (int kb = 0; kb < 4; kb++) {
    bf16x8 af = *(const bf16x8*)&A[(size_t)arow * H + kb * 32 + quad * 8];
    #pragma unroll
    for (int c = 0; c < 8; c++) {
      bf16x8 bfu = *(const bf16x8*)&Wp[(((kb * 8 + c) * 64) + lane) * 8];
      bf16x8 bfv = *(const bf16x8*)&Wp[16384 + (((kb * 8 + c) * 64) + lane) * 8];
      accu[c] = __builtin_amdgcn_mfma_f32_16x16x32_bf16(af, bfu, accu[c], 0, 0, 0);
      accv[c] = __builtin_amdgcn_mfma_f32_16x16x32_bf16(af, bfv, accv[c], 0, 0, 0);
    }
  }
  // C/D: n = lane&15, m = quad*4 + reg   (m89-verified mapping)
  #pragma unroll
  for (int c = 0; c < 8; c++) {
    int n = c * 16 + nn;
    float bub = bu[n], bvb = bv[n];
    #pragma unroll
    for (int r = 0; r < 4; r++) {
      int row = r0 + quad * 4 + r;
      if (row < M) {
        Cu[(size_t)row * H + n] = accu[c][r] + bub;
        Cv[(size_t)row * H + n] = accv[c][r] + bvb;
      }
    }
  }
}

// ======== fused scalar MLP, 32 rows/256 thr, double-buffered (R16 exact) ========
__global__ __launch_bounds__(256) __attribute__((amdgpu_waves_per_eu(2, 4)))
void scalar_mlp_fused(const float* __restrict__ A,
                      const float* __restrict__ W1, const float* __restrict__ b1,
                      const float* __restrict__ W2, const float* __restrict__ b2,
                      bf16* __restrict__ C, int M) {
  __shared__ float s_a[32][132];
  __shared__ float s_w[2][16][128];
  int i0 = blockIdx.x * 32;
  int tid = threadIdx.x;
  for (int idx = tid; idx < 32 * 128; idx += 256) {
    int r = idx >> 7, k = idx & 127;
    int gr = i0 + r;
    s_a[r][k] = (gr < M) ? A[(size_t)gr * H + k] : 0.0f;
  }
  int mq = tid >> 5, hq = tid & 31;
  int col = 4 * hq;
  int srow = tid >> 5, scol0 = (tid & 31) << 2;
  #pragma unroll
  for (int r = 0; r < 2; r++) {
    int row = srow + r * 8;
    *(float4*)&s_w[0][row][scol0] = *(const float4*)&W1[(size_t)row * H + scol0];
  }
  float acc[4][4] = {};
  for (int p = 0; p < 8; p++) {
    __syncthreads();
    if (p + 1 < 8) {
      #pragma unroll
      for (int r = 0; r < 2; r++) {
        int row = srow + r * 8;
        *(float4*)&s_w[(p + 1) & 1][row][scol0] =
            *(const float4*)&W1[(size_t)((p + 1) * 16 + row) * H + scol0];
      }
    }
    int kp = p * 16;
    #pragma unroll
    for (int kq = 0; kq < 4; kq++) {
      float4 av[4];
      #pragma unroll
      for (int i = 0; i < 4; i++) av[i] = *(const float4*)&s_a[4 * mq + i][kp + 4 * kq];
      #pragma unroll
      for (int k2 = 0; k2 < 4; k2++) {
        float4 w4 = *(const float4*)&s_w[p & 1][4 * kq + k2][4 * hq];
        #pragma unroll
        for (int i = 0; i < 4; i++) {
          float a = ((const float*)&av[i])[k2];
          acc[i][0] += a * w4.x; acc[i][1] += a * w4.y;
          acc[i][2] += a * w4.z; acc[i][3] += a * w4.w;
        }
      }
    }
  }
  float4 b14 = *(const float4*)&b1[col];
  __syncthreads();
  #pragma unroll
  for (int i = 0; i < 4; i++) {
    float4 o;
    o.x = silu_f(acc[i][0] + b14.x); o.y = silu_f(acc[i][1] + b14.y);
    o.z = silu_f(acc[i][2] + b14.z); o.w = silu_f(acc[i][3] + b14.w);
    *(float4*)&s_a[4 * mq + i][col] = o;
  }
  #pragma unroll
  for (int r = 0; r < 2; r++) {
    int row = srow + r * 8;
    *(float4*)&s_w[0][row][scol0] = *(const float4*)&W2[(size_t)row * F3H + scol0];
  }
  float a2[4][4] = {};
  for (int p = 0; p < 24; p++) {
    __syncthreads();
    if (p + 1 < 24) {
      int cpn = (p + 1) >> 3, kpn = ((p + 1) & 7) * 16;
      #pragma unroll
      for (int r = 0; r < 2; r++) {
        int row = srow + r * 8;
        *(float4*)&s_w[(p + 1) & 1][row][scol0] =
            *(const float4*)&W2[(size_t)(kpn + row) * F3H + cpn * 128 + scol0];
      }
    }
    int kp = (p & 7) * 16;
    #pragma unroll
    for (int kq = 0; kq < 4; kq++) {
      float4 av[4];
      #pragma unroll
      for (int i = 0; i < 4; i++) av[i] = *(const float4*)&s_a[4 * mq + i][kp + 4 * kq];
      #pragma unroll
      for (int k2 = 0; k2 < 4; k2++) {
        float4 w4 = *(const float4*)&s_w[p & 1][4 * kq + k2][4 * hq];
        #pragma unroll
        for (int i = 0; i < 4; i++) {
          float a = ((const float*)&av[i])[k2];
          a2[i][0] += a * w4.x; a2[i][1] += a * w4.y;
          a2[i][2] += a * w4.z; a2[i][3] += a * w4.w;
        }
      }
    }
    if ((p & 7) == 7) {
      int cp = p >> 3;
      float4 b24 = *(const float4*)&b2[cp * 128 + col];
      #pragma unroll
      for (int i = 0; i < 4; i++) {
        int gr = i0 + 4 * mq + i;
        if (gr < M) {
          float4 o;
          o.x = a2[i][0] + b24.x; o.y = a2[i][1] + b24.y;
          o.z = a2[i][2] + b24.z; o.w = a2[i][3] + b24.w;
          store_bf16x4(&C[(size_t)gr * F3H + cp * 128 + col], o);
        }
        a2[i][0] = 0.0f; a2[i][1] = 0.0f; a2[i][2] = 0.0f; a2[i][3] = 0.0f;
      }
    }
  }
}

// ======== fused update MLP + epilogue, 32 rows/256 thr, dbuf (R16 exact) ========
__global__ __launch_bounds__(256) __attribute__((amdgpu_waves_per_eu(2, 4)))
void update_fused(float* __restrict__ ns, float* __restrict__ nv,
                  bf16* __restrict__ nvb16,
                  const float* __restrict__ Uv, const float* __restrict__ Vv,
                  const float* __restrict__ W1, const float* __restrict__ b1,
                  const float* __restrict__ W2, const float* __restrict__ b2,
                  int M) {
  __shared__ float s_a[32][260];
  __shared__ float s_w[2][16][128];
  int i0 = blockIdx.x * 32;
  int tid = threadIdx.x;
  for (int idx = tid; idx < 32 * 256; idx += 256) {
    int r = idx >> 8, k = idx & 255;
    int gr = i0 + r;
    float val = 0.0f;
    if (gr < M) {
      if (k < H) {
        float v0 = Vv[(size_t)(3 * gr + 0) * H + k];
        float v1 = Vv[(size_t)(3 * gr + 1) * H + k];
        float v2 = Vv[(size_t)(3 * gr + 2) * H + k];
        val = sqrtf(v0 * v0 + v1 * v1 + v2 * v2);
      } else {
        val = ns[(size_t)gr * H + (k - H)];
      }
    }
    s_a[r][k] = val;
  }
  int mq = tid >> 5, hq = tid & 31;
  int col = 4 * hq;
  int srow = tid >> 5, scol0 = (tid & 31) << 2;
  #pragma unroll
  for (int r = 0; r < 2; r++) {
    int row = srow + r * 8;
    *(float4*)&s_w[0][row][scol0] = *(const float4*)&W1[(size_t)row * H + scol0];
  }
  float acc[4][4] = {};
  for (int p = 0; p < 16; p++) {
    __syncthreads();
    if (p + 1 < 16) {
      #pragma unroll
      for (int r = 0; r < 2; r++) {
        int row = srow + r * 8;
        *(float4*)&s_w[(p + 1) & 1][row][scol0] =
            *(const float4*)&W1[(size_t)((p + 1) * 16 + row) * H + scol0];
      }
    }
    int kp = p * 16;
    #pragma unroll
    for (int kq = 0; kq < 4; kq++) {
      float4 aa[4];
      #pragma unroll
      for (int i = 0; i < 4; i++) aa[i] = *(const float4*)&s_a[4 * mq + i][kp + 4 * kq];
      #pragma unroll
      for (int k2 = 0; k2 < 4; k2++) {
        float4 w4 = *(const float4*)&s_w[p & 1][4 * kq + k2][4 * hq];
        #pragma unroll
        for (int i = 0; i < 4; i++) {
          float a = ((const float*)&aa[i])[k2];
          acc[i][0] += a * w4.x; acc[i][1] += a * w4.y;
          acc[i][2] += a * w4.z; acc[i][3] += a * w4.w;
        }
      }
    }
  }
  float4 b14 = *(const float4*)&b1[col];
  __syncthreads();
  #pragma unroll
  for (int i = 0; i < 4; i++) {
    float4 o;
    o.x = silu_f(acc[i][0] + b14.x); o.y = silu_f(acc[i][1] + b14.y);
    o.z = silu_f(acc[i][2] + b14.z); o.w = silu_f(acc[i][3] + b14.w);
    *(float4*)&s_a[4 * mq + i][col] = o;
  }
  #pragma unroll
  for (int r = 0; r < 2; r++) {
    int row = srow + r * 8;
    *(float4*)&s_w[0][row][scol0] = *(const float4*)&W2[(size_t)row * F3H + scol0];
  }
  float g_av[4][4], g_as[4][4], g_ss[4][4];
  float a2[4][4] = {};
  for (int p = 0; p < 24; p++) {
    __syncthreads();
    if (p + 1 < 24) {
      int cpn = (p + 1) >> 3, kpn = ((p + 1) & 7) * 16;
      #pragma unroll
      for (int r = 0; r < 2; r++) {
        int row = srow + r * 8;
        *(float4*)&s_w[(p + 1) & 1][row][scol0] =
            *(const float4*)&W2[(size_t)(kpn + row) * F3H + cpn * 128 + scol0];
      }
    }
    int kp = (p & 7) * 16;
    #pragma unroll
    for (int kq = 0; kq < 4; kq++) {
      float4 aa[4];
      #pragma unroll
      for (int i = 0; i < 4; i++) aa[i] = *(const float4*)&s_a[4 * mq + i][kp + 4 * kq];
      #pragma unroll
      for (int k2 = 0; k2 < 4; k2++) {
        float4 w4 = *(const float4*)&s_w[p & 1][4 * kq + k2][4 * hq];
        #pragma unroll
        for (int i = 0; i < 4; i++) {
          float a = ((const float*)&aa[i])[k2];
          a2[i][0] += a * w4.x; a2[i][1] += a * w4.y;
          a2[i][2] += a * w4.z; a2[i][3] += a * w4.w;
        }
      }
    }
    if ((p & 7) == 7) {
      int cp = p >> 3;
      float4 b24 = *(const float4*)&b2[cp * 128 + col];
      #pragma unroll
      for (int i = 0; i < 4; i++) {
        float v0 = a2[i][0] + b24.x, v1 = a2[i][1] + b24.y;
        float v2 = a2[i][2] + b24.z, v3 = a2[i][3] + b24.w;
        if (cp == 0) { g_av[i][0] = v0; g_av[i][1] = v1; g_av[i][2] = v2; g_av[i][3] = v3; }
        if (cp == 1) { g_as[i][0] = v0; g_as[i][1] = v1; g_as[i][2] = v2; g_as[i][3] = v3; }
        if (cp == 2) { g_ss[i][0] = v0; g_ss[i][1] = v1; g_ss[i][2] = v2; g_ss[i][3] = v3; }
        a2[i][0] = 0.0f; a2[i][1] = 0.0f; a2[i][2] = 0.0f; a2[i][3] = 0.0f;
      }
    }
  }
  #pragma unroll
  for (int i = 0; i < 4; i++) {
    int gr = i0 + 4 * mq + i;
    if (gr < M) {
      float4 u0 = *(const float4*)&Uv[(size_t)(3 * gr + 0) * H + col];
      float4 u1 = *(const float4*)&Uv[(size_t)(3 * gr + 1) * H + col];
      float4 u2 = *(const float4*)&Uv[(size_t)(3 * gr + 2) * H + col];
      float4 v0 = *(const float4*)&Vv[(size_t)(3 * gr + 0) * H + col];
      float4 v1 = *(const float4*)&Vv[(size_t)(3 * gr + 1) * H + col];
      float4 v2 = *(const float4*)&Vv[(size_t)(3 * gr + 2) * H + col];
      float4 dot;
      dot.x = u0.x * v0.x + u1.x * v1.x + u2.x * v2.x;
      dot.y = u0.y * v0.y + u1.y * v1.y + u2.y * v2.y;
      dot.z = u0.z * v0.z + u1.z * v1.z + u2.z * v2.z;
      dot.w = u0.w * v0.w + u1.w * v1.w + u2.w * v2.w;
      float4 nsv = *(float4*)&ns[(size_t)gr * H + col];
      nsv.x += g_as[i][0] * dot.x + g_ss[i][0];
      nsv.y += g_as[i][1] * dot.y + g_ss[i][1];
      nsv.z += g_as[i][2] * dot.z + g_ss[i][2];
      nsv.w += g_as[i][3] * dot.w + g_ss[i][3];
      *(float4*)&ns[(size_t)gr * H + col] = nsv;
      float4 n0 = *(float4*)&nv[(size_t)(3 * gr + 0) * H + col];
      float4 n1 = *(float4*)&nv[(size_t)(3 * gr + 1) * H + col];
      float4 n2 = *(float4*)&nv[(size_t)(3 * gr + 2) * H + col];
      n0.x += g_av[i][0] * u0.x; n0.y += g_av[i][1] * u0.y; n0.z += g_av[i][2] * u0.z; n0.w += g_av[i][3] * u0.w;
      n1.x += g_av[i][0] * u1.x; n1.y += g_av[i][1] * u1.y; n1.z += g_av[i][2] * u1.z; n1.w += g_av[i][3] * u1.w;
      n2.x += g_av[i][0] * u2.x; n2.y += g_av[i][1] * u2.y; n2.z += g_av[i][2] * u2.z; n2.w += g_av[i][3] * u2.w;
      *(float4*)&nv[(size_t)(3 * gr + 0) * H + col] = n0;
      *(float4*)&nv[(size_t)(3 * gr + 1) * H + col] = n1;
      *(float4*)&nv[(size_t)(3 * gr + 2) * H + col] = n2;
      store_bf16x4(&nvb16[((size_t)gr * 3 + 0) * H + col], n0);
      store_bf16x4(&nvb16[((size_t)gr * 3 + 1) * H + col], n1);
      store_bf16x4(&nvb16[((size_t)gr * 3 + 2) * H + col], n2);
    }
  }
}

// ======== fused readout, 32 rows/256 thr, dbuf (R16 exact) ========
__global__ __launch_bounds__(256) __attribute__((amdgpu_waves_per_eu(2, 4)))
void readout_fused(const float* __restrict__ A,
                   const float* __restrict__ W1, const float* __restrict__ b1,
                   const float* __restrict__ W2, const float* __restrict__ b2,
                   float* __restrict__ C, int M) {
  __shared__ float s_a[32][132];
  __shared__ float s_w[2][16][128];
  int i0 = blockIdx.x * 32;
  int tid = threadIdx.x;
  for (int idx = tid; idx < 32 * 128; idx += 256) {
    int r = idx >> 7, k = idx & 127;
    int gr = i0 + r;
    s_a[r][k] = (gr < M) ? A[(size_t)gr * H + k] : 0.0f;
  }
  int mq = tid >> 5, hq = tid & 31;
  int col = 4 * hq;
  int srow = tid >> 5, scol0 = (tid & 31) << 2;
  #pragma unroll
  for (int r = 0; r < 2; r++) {
    int row = srow + r * 8;
    *(float4*)&s_w[0][row][scol0] = *(const float4*)&W1[(size_t)row * H + scol0];
  }
  float acc[4][4] = {};
  for (int p = 0; p < 8; p++) {
    __syncthreads();
    if (p + 1 < 8) {
      #pragma unroll
      for (int r = 0; r < 2; r++) {
        int row = srow + r * 8;
        *(float4*)&s_w[(p + 1) & 1][row][scol0] =
            *(const float4*)&W1[(size_t)((p + 1) * 16 + row) * H + scol0];
      }
    }
    int kp = p * 16;
    #pragma unroll
    for (int kq = 0; kq < 4; kq++) {
      float4 av[4];
      #pragma unroll
      for (int i = 0; i < 4; i++) av[i] = *(const float4*)&s_a[4 * mq + i][kp + 4 * kq];
      #pragma unroll
      for (int k2 = 0; k2 < 4; k2++) {
        float4 w4 = *(const float4*)&s_w[p & 1][4 * kq + k2][4 * hq];
        #pragma unroll
        for (int i = 0; i < 4; i++) {
          float a = ((const float*)&av[i])[k2];
          acc[i][0] += a * w4.x; acc[i][1] += a * w4.y;
          acc[i][2] += a * w4.z; acc[i][3] += a * w4.w;
        }
      }
    }
  }
  float4 b14 = *(const float4*)&b1[col];
  __syncthreads();
  #pragma unroll
  for (int i = 0; i < 4; i++) {
    float4 o;
    o.x = silu_f(acc[i][0] + b14.x); o.y = silu_f(acc[i][1] + b14.y);
    o.z = silu_f(acc[i][2] + b14.z); o.w = silu_f(acc[i][3] + b14.w);
    *(float4*)&s_a[4 * mq + i][col] = o;
  }
  #pragma unroll
  for (int r = 0; r < 2; r++) {
    int row = srow + r * 8;
    *(float4*)&s_w[0][row][scol0] = *(const float4*)&W2[(size_t)row * H + scol0];
  }
  float a2[4][4] = {};
  for (int p = 0; p < 8; p++) {
    __syncthreads();
    if (p + 1 < 8) {
      #pragma unroll
      for (int r = 0; r < 2; r++) {
        int row = srow + r * 8;
        *(float4*)&s_w[(p + 1) & 1][row][scol0] =
            *(const float4*)&W2[(size_t)((p + 1) * 16 + row) * H + scol0];
      }
    }
    int kp = p * 16;
    #pragma unroll
    for (int kq = 0; kq < 4; kq++) {
      float4 av[4];
      #pragma unroll
      for (int i = 0; i < 4; i++) av[i] = *(const float4*)&s_a[4 * mq + i][kp + 4 * kq];
      #pragma unroll
      for (int k2 = 0; k2 < 4; k2++) {
        float4 w4 = *(const float4*)&s_w[p & 1][4 * kq + k2][4 * hq];
        #pragma unroll
        for (int i = 0; i < 4; i++) {
          float a = ((const float*)&av[i])[k2];
          a2[i][0] += a * w4.x; a2[i][1] += a * w4.y;
          a2[i][2] += a * w4.z; a2[i][3] += a * w4.w;
        }
      }
    }
  }
  float4 b24 = *(const float4*)&b2[col];
  #pragma unroll
  for (int i = 0; i < 4; i++) {
    int gr = i0 + 4 * mq + i;
    if (gr < M) {
      float4 o;
      o.x = a2[i][0] + b24.x; o.y = a2[i][1] + b24.y;
      o.z = a2[i][2] + b24.z; o.w = a2[i][3] + b24.w;
      *(float4*)&C[(size_t)gr * H + col] = o;
    }
  }
}

// ---------------- message: bf16 gathers; fp32 state; + bf16 shadow of nvB ----------------
template<bool HASNV>
__global__ __launch_bounds__(128, 4) void message3(
    const int* __restrict__ srcs, const int* __restrict__ rowstart,
    const int* __restrict__ cnt, const float* __restrict__ geo,
    const float* __restrict__ Wf, const float* __restrict__ bfb,
    const bf16* __restrict__ so, const bf16* __restrict__ nvb16,
    const float* __restrict__ nvA,
    float* __restrict__ ns, float* __restrict__ nvB,
    bf16* __restrict__ nvmsg16, int N) {
  int i = blockIdx.x;
  int h = threadIdx.x;

  float wf0[E_RBF], wf1[E_RBF], wf2[E_RBF];
  #pragma unroll
  for (int k = 0; k < E_RBF; k++) {
    wf0[k] = Wf[k * F3H + h];
    wf1[k] = Wf[k * F3H + H + h];
    wf2[k] = Wf[k * F3H + 2 * H + h];
  }
  float bb0 = bfb[h], bb1 = bfb[H + h], bb2 = bfb[2 * H + h];

  float accs = 0.0f, a0 = 0.0f, a1 = 0.0f, a2 = 0.0f;
  int jlo = rowstart[i], jhi = jlo + cnt[i];
  for (int j = jlo; j < jhi; j++) {
    int src = srcs[j];
    const float* g = geo + (size_t)j * 24;
    float gg[24];
    #pragma unroll
    for (int q = 0; q < 6; q++) *(float4*)&gg[4 * q] = *(const float4*)&g[4 * q];

    float fc = gg[23];
    float f0 = bb0 * fc, f1 = bb1 * fc, f2 = bb2 * fc;
    #pragma unroll
    for (int k = 0; k < E_RBF; k++) {
      float rk = gg[k];
      f0 += rk * wf0[k];
      f1 += rk * wf1[k];
      f2 += rk * wf2[k];
    }
    float u0 = gg[20], u1 = gg[21], u2 = gg[22];

    const bf16* sop = so + (size_t)src * F3H;
    float gsv = f0 * b2f(sop[h]);
    float gev = f1 * b2f(sop[H + h]);
    accs += f2 * b2f(sop[2 * H + h]);

    if (HASNV) {
      const bf16* nvp = nvb16 + (size_t)src * F3H;
      a0 += b2f(nvp[h])         * gsv + gev * u0;
      a1 += b2f(nvp[H + h])     * gsv + gev * u1;
      a2 += b2f(nvp[2 * H + h]) * gsv + gev * u2;
    } else {
      a0 += gev * u0;
      a1 += gev * u1;
      a2 += gev * u2;
    }
  }

  ns[(size_t)i * H + h] += accs;
  float o0, o1, o2;
  if (HASNV) {
    const float* nvi = nvA + (size_t)i * F3H;
    o0 = nvi[h] + a0;
    o1 = nvi[H + h] + a1;
    o2 = nvi[2 * H + h] + a2;
  } else {
    o0 = a0; o1 = a1; o2 = a2;
  }
  nvB[(size_t)i * F3H + h]         = o0;
  nvB[(size_t)i * F3H + H + h]     = o1;
  nvB[(size_t)i * F3H + 2 * H + h] = o2;
  nvmsg16[(size_t)i * F3H + h]         = __float2bfloat16(o0);
  nvmsg16[(size_t)i * F3H + H + h]     = __float2bfloat16(o1);
  nvmsg16[(size_t)i * F3H + 2 * H + h] = __float2bfloat16(o2);
}

extern "C" void kernel_launch(void* const* d_in, const int* in_sizes, int n_in,
                              void* d_out, int out_size, void* d_ws, size_t ws_size,
                              hipStream_t stream) {
  const int*   z     = (const int*)d_in[0];
  const int*   edge  = (const int*)d_in[1];
  const float* ediff = (const float*)d_in[2];
  const float* edist = (const float*)d_in[3];
  const float* embed = (const float*)d_in[4];
  const float* mfw   = (const float*)d_in[5];
  const float* mfb   = (const float*)d_in[6];
  const float* mw1   = (const float*)d_in[7];
  const float* mb1   = (const float*)d_in[8];
  const float* mw2   = (const float*)d_in[9];
  const float* mb2   = (const float*)d_in[10];
  const float* uUw   = (const float*)d_in[11];
  const float* uUb   = (const float*)d_in[12];
  const float* uVw   = (const float*)d_in[13];
  const float* uVb   = (const float*)d_in[14];
  const float* uw1   = (const float*)d_in[15];
  const float* ub1   = (const float*)d_in[16];
  const float* uw2   = (const float*)d_in[17];
  const float* ub2   = (const float*)d_in[18];
  const float* rw1   = (const float*)d_in[19];
  const float* rb1   = (const float*)d_in[20];
  const float* rw2   = (const float*)d_in[21];
  const float* rb2   = (const float*)d_in[22];

  const int N  = in_sizes[0];   // 10000
  const int nE = in_sizes[3];   // 160000

  float* ws = (float*)d_ws;
  size_t off = 0;
  float* ns      = ws + off; off += (size_t)N * H;
  float* nvA     = ws + off; off += (size_t)N * F3H;
  float* nvB     = ws + off; off += (size_t)N * F3H;
  float* Vv      = ws + off; off += (size_t)N * F3H;
  float* geo     = ws + off; off += (size_t)nE * 24;
  bf16* so       = (bf16*)(ws + off); off += (size_t)N * F3H / 2;
  bf16* nvb16    = (bf16*)(ws + off); off += (size_t)N * F3H / 2;
  bf16* nvmsg16  = (bf16*)(ws + off); off += (size_t)N * F3H / 2;
  bf16* wpack    = (bf16*)(ws + off); off += 3 * 2 * 16384 / 2;
  int* srcs     = (int*)(ws + off); off += nE;
  int* cnt      = (int*)(ws + off); off += N;
  int* rowstart = (int*)(ws + off); off += N;
  int* cur      = (int*)(ws + off); off += N;
  int* elist    = (int*)(ws + off); off += nE;

  const int tilesN = (N + 31) / 32;            // 313
  const int uvBlks = (3 * N + 63) / 64;        // 469

  (void)hipMemsetAsync(cnt, 0, (size_t)N * sizeof(int), stream);
  csr_hist<<<(nE + 255) / 256, 256, 0, stream>>>(edge, cnt, nE);
  csr_scan<<<1, 256, 0, stream>>>(cnt, rowstart, cur, N);
  csr_fill<<<(nE + 255) / 256, 256, 0, stream>>>(edge, cur, elist, nE);
  edge_pack<<<(nE + 255) / 256, 256, 0, stream>>>(elist, edge, edist, ediff, srcs, geo, nE);
  pack_w<<<48, 256, 0, stream>>>(uUw, uVw, wpack);

  node_init<<<N, H, 0, stream>>>(z, embed, ns, N);

  float* nv_cur = nvA;
  float* nv_nxt = nvB;
  for (int l = 0; l < NLAYER; l++) {
    scalar_mlp_fused<<<tilesN, 256, 0, stream>>>(
        ns, mw1 + (size_t)l * H * H, mb1 + (size_t)l * H,
        mw2 + (size_t)l * H * F3H, mb2 + (size_t)l * F3H, so, N);

    if (l == 0)
      message3<false><<<N, H, 0, stream>>>(srcs, rowstart, cnt, geo,
                                           mfw + (size_t)l * E_RBF * F3H, mfb + (size_t)l * F3H,
                                           so, nvb16, nv_cur, ns, nv_nxt, nvmsg16, N);
    else
      message3<true><<<N, H, 0, stream>>>(srcs, rowstart, cnt, geo,
                                          mfw + (size_t)l * E_RBF * F3H, mfb + (size_t)l * F3H,
                                          so, nvb16, nv_cur, ns, nv_nxt, nvmsg16, N);

    float* Uv = nv_cur;  // dead after message3 — reuse as Uv scratch
    gemm_uv_mfma<<<uvBlks, 256, 0, stream>>>(
        nvmsg16, wpack + (size_t)l * 2 * 16384,
        uUb + (size_t)l * H, uVb + (size_t)l * H,
        Uv, Vv, 3 * N);

    update_fused<<<tilesN, 256, 0, stream>>>(
        ns, nv_nxt, nvb16, Uv, Vv,
        uw1 + (size_t)l * 2 * H * H, ub1 + (size_t)l * H,
        uw2 + (size_t)l * H * F3H, ub2 + (size_t)l * F3H, N);

    float* t = nv_cur; nv_cur = nv_nxt; nv_nxt = t;
  }

  readout_fused<<<tilesN, 256, 0, stream>>>(ns, rw1, rb1, rw2, rb2, (float*)d_out, N);
}

// Round 19
// 637.079 us; speedup vs baseline: 1.8910x; 1.1211x over previous
//
#include <hip/hip_runtime.h>
#include <hip/hip_bf16.h>

typedef __hip_bfloat16 bf16;
typedef __attribute__((ext_vector_type(8))) short bf16x8;
typedef __attribute__((ext_vector_type(4))) float f32x4;

#define H 128
#define F3H 384
#define E_RBF 20
#define NLAYER 3

__device__ __forceinline__ float silu_f(float x) { return x / (1.0f + __expf(-x)); }
__device__ __forceinline__ float b2f(bf16 x) { return __bfloat162float(x); }

constexpr float PI_F = 3.14159265358979323846f;
constexpr float CUT = 5.0f;

// ---------------- CSR build ----------------
__global__ __launch_bounds__(256) void csr_hist(
    const int* __restrict__ edge, int* __restrict__ cnt, int nE) {
  int e = blockIdx.x * blockDim.x + threadIdx.x;
  if (e < nE) atomicAdd(&cnt[edge[2 * e]], 1);
}

__global__ __launch_bounds__(256) void csr_scan(
    const int* __restrict__ cnt, int* __restrict__ rowstart, int* __restrict__ cur, int N) {
  __shared__ int part[256];
  int t = threadIdx.x;
  int chunk = (N + 255) / 256;
  int lo = t * chunk; if (lo > N) lo = N;
  int hi = lo + chunk; if (hi > N) hi = N;
  int s = 0;
  for (int i = lo; i < hi; i++) s += cnt[i];
  part[t] = s;
  __syncthreads();
  if (t == 0) {
    int r = 0;
    for (int i = 0; i < 256; i++) { int v = part[i]; part[i] = r; r += v; }
  }
  __syncthreads();
  int r = part[t];
  for (int i = lo; i < hi; i++) { rowstart[i] = r; cur[i] = r; r += cnt[i]; }
}

__global__ __launch_bounds__(256) void csr_fill(
    const int* __restrict__ edge, int* __restrict__ cur, int* __restrict__ elist, int nE) {
  int e = blockIdx.x * blockDim.x + threadIdx.x;
  if (e < nE) {
    int d = edge[2 * e];
    int p = atomicAdd(&cur[d], 1);
    elist[p] = e;
  }
}

// ---------------- edge geometry pack ----------------
__global__ __launch_bounds__(256) void edge_pack(
    const int* __restrict__ elist, const int* __restrict__ edge,
    const float* __restrict__ edist, const float* __restrict__ ediff,
    int* __restrict__ srcs, float* __restrict__ geo, int nE) {
  int j = blockIdx.x * blockDim.x + threadIdx.x;
  if (j >= nE) return;
  int e = elist[j];
  srcs[j] = edge[2 * e + 1];
  float d = edist[e];
  float inv = 1.0f / d;
  float th = d * (PI_F / CUT);
  float s1 = sinf(th), c1 = cosf(th);
  float fc = (d < CUT) ? 0.5f * (c1 + 1.0f) : 0.0f;
  float* g = geo + (size_t)j * 24;
  float twoc = 2.0f * c1;
  float skp = 0.0f, sk = s1;
  #pragma unroll
  for (int k = 0; k < E_RBF; k++) {
    g[k] = sk * inv * fc;
    float nx = twoc * sk - skp;
    skp = sk; sk = nx;
  }
  g[20] = ediff[3 * (size_t)e] * inv;
  g[21] = ediff[3 * (size_t)e + 1] * inv;
  g[22] = ediff[3 * (size_t)e + 2] * inv;
  g[23] = fc;
}

// ---------------- node init ----------------
__global__ __launch_bounds__(H) void node_init(
    const int* __restrict__ z, const float* __restrict__ embed,
    float* __restrict__ ns, int N) {
  int i = blockIdx.x;
  int h = threadIdx.x;
  ns[(size_t)i * H + h] = embed[(size_t)z[i] * H + h];
}

__device__ __forceinline__ void store_bf16x4(bf16* p, float4 v) {
  union { bf16 b[4]; ushort4 u; } t;
  t.b[0] = __float2bfloat16(v.x);
  t.b[1] = __float2bfloat16(v.y);
  t.b[2] = __float2bfloat16(v.z);
  t.b[3] = __float2bfloat16(v.w);
  *(ushort4*)p = t.u;
}

// ---------------- pack U/V weights into MFMA B-fragment layout ----------------
__global__ __launch_bounds__(256) void pack_w(
    const float* __restrict__ Wu, const float* __restrict__ Wv,
    bf16* __restrict__ wp) {
  int t = blockIdx.x * blockDim.x + threadIdx.x;   // 12288 total
  if (t >= 3 * 2 * 4 * 8 * 64) return;
  int lane = t & 63;
  int c    = (t >> 6) & 7;
  int kb   = (t >> 9) & 3;
  int mat  = (t >> 11) & 1;
  int l    = t >> 12;
  const float* src = (mat ? Wv : Wu) + (size_t)l * H * H;
  bf16* dst = wp + ((size_t)(l * 2 + mat) * 16384) + (((kb * 8 + c) * 64 + lane) * 8);
  int quad = lane >> 4;
  int n = c * 16 + (lane & 15);
  #pragma unroll
  for (int j = 0; j < 8; j++) {
    int k = kb * 32 + quad * 8 + j;
    dst[j] = __float2bfloat16(src[(size_t)k * H + n]);
  }
}

// ---------------- generic B-fragment packer: src [L][K][ncols] fp32 -> bf16 frags ----------------
// dst layer stride = K*ncols; within: ((kb*(ncols/16) + c)*64 + lane)*8 + j
__global__ __launch_bounds__(256) void pack_b(
    const float* __restrict__ src, bf16* __restrict__ dst,
    int K, int ncols, int L) {
  int kblocks = K >> 5, ncols16 = ncols >> 4;
  int total = L * kblocks * ncols16 * 64;
  int t = blockIdx.x * blockDim.x + threadIdx.x;
  if (t >= total) return;
  int lane = t & 63;
  int idx = t >> 6;
  int c = idx % ncols16; idx /= ncols16;
  int kb = idx % kblocks; idx /= kblocks;
  int l = idx;
  const float* s = src + (size_t)l * K * ncols;
  bf16* d = dst + (size_t)l * K * ncols + (((kb * ncols16 + c) * 64 + lane) * 8);
  int quad = lane >> 4;
  int n = c * 16 + (lane & 15);
  #pragma unroll
  for (int j = 0; j < 8; j++) {
    int k = kb * 32 + quad * 8 + j;
    d[j] = __float2bfloat16(s[(size_t)k * ncols + n]);
  }
}

// ---------------- MFMA dual GEMM: Uv/Vv ----------------
__global__ __launch_bounds__(256) void gemm_uv_mfma(
    const bf16* __restrict__ A, const bf16* __restrict__ Wp,
    const float* __restrict__ bu, const float* __restrict__ bv,
    float* __restrict__ Cu, float* __restrict__ Cv, int M) {
  int wave = threadIdx.x >> 6;
  int lane = threadIdx.x & 63;
  int r0 = blockIdx.x * 64 + wave * 16;
  int quad = lane >> 4;
  int nn = lane & 15;
  int arow = r0 + nn;
  if (arow >= M) arow = M - 1;
  f32x4 accu[8] = {};
  f32x4 accv[8] = {};
  for (int kb = 0; kb < 4; kb++) {
    bf16x8 af = *(const bf16x8*)&A[(size_t)arow * H + kb * 32 + quad * 8];
    #pragma unroll
    for (int c = 0; c < 8; c++) {
      bf16x8 bfu = *(const bf16x8*)&Wp[(((kb * 8 + c) * 64) + lane) * 8];
      bf16x8 bfv = *(const bf16x8*)&Wp[16384 + (((kb * 8 + c) * 64) + lane) * 8];
      accu[c] = __builtin_amdgcn_mfma_f32_16x16x32_bf16(af, bfu, accu[c], 0, 0, 0);
      accv[c] = __builtin_amdgcn_mfma_f32_16x16x32_bf16(af, bfv, accv[c], 0, 0, 0);
    }
  }
  #pragma unroll
  for (int c = 0; c < 8; c++) {
    int n = c * 16 + nn;
    float bub = bu[n], bvb = bv[n];
    #pragma unroll
    for (int r = 0; r < 4; r++) {
      int row = r0 + quad * 4 + r;
      if (row < M) {
        Cu[(size_t)row * H + n] = accu[c][r] + bub;
        Cv[(size_t)row * H + n] = accv[c][r] + bvb;
      }
    }
  }
}

// ---------------- vnorm -> A2[:,0:128] bf16 ----------------
__global__ __launch_bounds__(256) void vnorm_a2(
    const float* __restrict__ Vv, bf16* __restrict__ A2, int N) {
  int t = blockIdx.x * blockDim.x + threadIdx.x;
  if (t >= N * H) return;
  int i = t >> 7, h = t & 127;
  float v0 = Vv[(size_t)(3 * i + 0) * H + h];
  float v1 = Vv[(size_t)(3 * i + 1) * H + h];
  float v2 = Vv[(size_t)(3 * i + 2) * H + h];
  A2[(size_t)i * 256 + h] = __float2bfloat16(sqrtf(v0 * v0 + v1 * v1 + v2 * v2));
}

// ---------------- MFMA update-MLP stage 1: m1 = silu(A2@W1+b1) -> bf16 ----------------
// block 256 = 4 waves: wave (rowg=w>>1 16-rows, ch=w&1 col-half of 128 cols). K=256.
__global__ __launch_bounds__(256) void gemm_m1_mfma(
    const bf16* __restrict__ A2, const bf16* __restrict__ Wp,
    const float* __restrict__ b1, bf16* __restrict__ m1, int M) {
  int wave = threadIdx.x >> 6, lane = threadIdx.x & 63;
  int rowg = wave >> 1, ch = wave & 1;
  int r0 = blockIdx.x * 32 + rowg * 16;
  int quad = lane >> 4, nn = lane & 15;
  int arow = r0 + nn; if (arow >= M) arow = M - 1;
  f32x4 acc[4] = {};
  for (int kb = 0; kb < 8; kb++) {
    bf16x8 af = *(const bf16x8*)&A2[(size_t)arow * 256 + kb * 32 + quad * 8];
    #pragma unroll
    for (int c = 0; c < 4; c++) {
      int cg = ch * 4 + c;
      bf16x8 bw = *(const bf16x8*)&Wp[(((kb * 8 + cg) * 64) + lane) * 8];
      acc[c] = __builtin_amdgcn_mfma_f32_16x16x32_bf16(af, bw, acc[c], 0, 0, 0);
    }
  }
  #pragma unroll
  for (int c = 0; c < 4; c++) {
    int n = (ch * 4 + c) * 16 + nn;
    float bb = b1[n];
    #pragma unroll
    for (int r = 0; r < 4; r++) {
      int row = r0 + quad * 4 + r;
      if (row < M) m1[(size_t)row * H + n] = __float2bfloat16(silu_f(acc[c][r] + bb));
    }
  }
}

// ---------------- MFMA update-MLP stage 2 + gating epilogue ----------------
// mo = m1@W2+b2 (384 cols = 24 tiles; avv=c, asv=c+8, ass=c+16); epilogue inline.
__global__ __launch_bounds__(256) void gemm_mo_ep(
    const bf16* __restrict__ m1, const bf16* __restrict__ Wp,
    const float* __restrict__ b2,
    float* __restrict__ ns, float* __restrict__ nv, bf16* __restrict__ nvb16,
    const float* __restrict__ Uv, const float* __restrict__ Vv, int M) {
  int wave = threadIdx.x >> 6, lane = threadIdx.x & 63;
  int rowg = wave >> 1, ch = wave & 1;
  int r0 = blockIdx.x * 32 + rowg * 16;
  int quad = lane >> 4, nn = lane & 15;
  int arow = r0 + nn; if (arow >= M) arow = M - 1;
  f32x4 aav[4] = {}, aas[4] = {}, asz[4] = {};
  for (int kb = 0; kb < 4; kb++) {
    bf16x8 af = *(const bf16x8*)&m1[(size_t)arow * H + kb * 32 + quad * 8];
    #pragma unroll
    for (int c = 0; c < 4; c++) {
      int cg = ch * 4 + c;
      bf16x8 b0 = *(const bf16x8*)&Wp[(((kb * 24 + cg) * 64) + lane) * 8];
      bf16x8 b1v = *(const bf16x8*)&Wp[(((kb * 24 + cg + 8) * 64) + lane) * 8];
      bf16x8 b2v = *(const bf16x8*)&Wp[(((kb * 24 + cg + 16) * 64) + lane) * 8];
      aav[c] = __builtin_amdgcn_mfma_f32_16x16x32_bf16(af, b0, aav[c], 0, 0, 0);
      aas[c] = __builtin_amdgcn_mfma_f32_16x16x32_bf16(af, b1v, aas[c], 0, 0, 0);
      asz[c] = __builtin_amdgcn_mfma_f32_16x16x32_bf16(af, b2v, asz[c], 0, 0, 0);
    }
  }
  #pragma unroll
  for (int c = 0; c < 4; c++) {
    int n = (ch * 4 + c) * 16 + nn;
    float bav = b2[n], bas = b2[H + n], bss = b2[2 * H + n];
    #pragma unroll
    for (int r = 0; r < 4; r++) {
      int row = r0 + quad * 4 + r;
      if (row < M) {
        float avv = aav[c][r] + bav;
        float asv = aas[c][r] + bas;
        float ass = asz[c][r] + bss;
        float u0 = Uv[(size_t)(3 * row + 0) * H + n];
        float u1 = Uv[(size_t)(3 * row + 1) * H + n];
        float u2 = Uv[(size_t)(3 * row + 2) * H + n];
        float v0 = Vv[(size_t)(3 * row + 0) * H + n];
        float v1 = Vv[(size_t)(3 * row + 1) * H + n];
        float v2 = Vv[(size_t)(3 * row + 2) * H + n];
        float dot = u0 * v0 + u1 * v1 + u2 * v2;
        ns[(size_t)row * H + n] += asv * dot + ass;
        float n0 = nv[(size_t)(3 * row + 0) * H + n] + avv * u0;
        float n1 = nv[(size_t)(3 * row + 1) * H + n] + avv * u1;
        float n2 = nv[(size_t)(3 * row + 2) * H + n] + avv * u2;
        nv[(size_t)(3 * row + 0) * H + n] = n0;
        nv[(size_t)(3 * row + 1) * H + n] = n1;
        nv[(size_t)(3 * row + 2) * H + n] = n2;
        nvb16[(size_t)(3 * row + 0) * H + n] = __float2bfloat16(n0);
        nvb16[(size_t)(3 * row + 1) * H + n] = __float2bfloat16(n1);
        nvb16[(size_t)(3 * row + 2) * H + n] = __float2bfloat16(n2);
      }
    }
  }
}

// ======== fused scalar MLP, 32 rows/256 thr, double-buffered (R16 exact) ========
__global__ __launch_bounds__(256) __attribute__((amdgpu_waves_per_eu(2, 4)))
void scalar_mlp_fused(const float* __restrict__ A,
                      const float* __restrict__ W1, const float* __restrict__ b1,
                      const float* __restrict__ W2, const float* __restrict__ b2,
                      bf16* __restrict__ C, int M) {
  __shared__ float s_a[32][132];
  __shared__ float s_w[2][16][128];
  int i0 = blockIdx.x * 32;
  int tid = threadIdx.x;
  for (int idx = tid; idx < 32 * 128; idx += 256) {
    int r = idx >> 7, k = idx & 127;
    int gr = i0 + r;
    s_a[r][k] = (gr < M) ? A[(size_t)gr * H + k] : 0.0f;
  }
  int mq = tid >> 5, hq = tid & 31;
  int col = 4 * hq;
  int srow = tid >> 5, scol0 = (tid & 31) << 2;
  #pragma unroll
  for (int r = 0; r < 2; r++) {
    int row = srow + r * 8;
    *(float4*)&s_w[0][row][scol0] = *(const float4*)&W1[(size_t)row * H + scol0];
  }
  float acc[4][4] = {};
  for (int p = 0; p < 8; p++) {
    __syncthreads();
    if (p + 1 < 8) {
      #pragma unroll
      for (int r = 0; r < 2; r++) {
        int row = srow + r * 8;
        *(float4*)&s_w[(p + 1) & 1][row][scol0] =
            *(const float4*)&W1[(size_t)((p + 1) * 16 + row) * H + scol0];
      }
    }
    int kp = p * 16;
    #pragma unroll
    for (int kq = 0; kq < 4; kq++) {
      float4 av[4];
      #pragma unroll
      for (int i = 0; i < 4; i++) av[i] = *(const float4*)&s_a[4 * mq + i][kp + 4 * kq];
      #pragma unroll
      for (int k2 = 0; k2 < 4; k2++) {
        float4 w4 = *(const float4*)&s_w[p & 1][4 * kq + k2][4 * hq];
        #pragma unroll
        for (int i = 0; i < 4; i++) {
          float a = ((const float*)&av[i])[k2];
          acc[i][0] += a * w4.x; acc[i][1] += a * w4.y;
          acc[i][2] += a * w4.z; acc[i][3] += a * w4.w;
        }
      }
    }
  }
  float4 b14 = *(const float4*)&b1[col];
  __syncthreads();
  #pragma unroll
  for (int i = 0; i < 4; i++) {
    float4 o;
    o.x = silu_f(acc[i][0] + b14.x); o.y = silu_f(acc[i][1] + b14.y);
    o.z = silu_f(acc[i][2] + b14.z); o.w = silu_f(acc[i][3] + b14.w);
    *(float4*)&s_a[4 * mq + i][col] = o;
  }
  #pragma unroll
  for (int r = 0; r < 2; r++) {
    int row = srow + r * 8;
    *(float4*)&s_w[0][row][scol0] = *(const float4*)&W2[(size_t)row * F3H + scol0];
  }
  float a2[4][4] = {};
  for (int p = 0; p < 24; p++) {
    __syncthreads();
    if (p + 1 < 24) {
      int cpn = (p + 1) >> 3, kpn = ((p + 1) & 7) * 16;
      #pragma unroll
      for (int r = 0; r < 2; r++) {
        int row = srow + r * 8;
        *(float4*)&s_w[(p + 1) & 1][row][scol0] =
            *(const float4*)&W2[(size_t)(kpn + row) * F3H + cpn * 128 + scol0];
      }
    }
    int kp = (p & 7) * 16;
    #pragma unroll
    for (int kq = 0; kq < 4; kq++) {
      float4 av[4];
      #pragma unroll
      for (int i = 0; i < 4; i++) av[i] = *(const float4*)&s_a[4 * mq + i][kp + 4 * kq];
      #pragma unroll
      for (int k2 = 0; k2 < 4; k2++) {
        float4 w4 = *(const float4*)&s_w[p & 1][4 * kq + k2][4 * hq];
        #pragma unroll
        for (int i = 0; i < 4; i++) {
          float a = ((const float*)&av[i])[k2];
          a2[i][0] += a * w4.x; a2[i][1] += a * w4.y;
          a2[i][2] += a * w4.z; a2[i][3] += a * w4.w;
        }
      }
    }
    if ((p & 7) == 7) {
      int cp = p >> 3;
      float4 b24 = *(const float4*)&b2[cp * 128 + col];
      #pragma unroll
      for (int i = 0; i < 4; i++) {
        int gr = i0 + 4 * mq + i;
        if (gr < M) {
          float4 o;
          o.x = a2[i][0] + b24.x; o.y = a2[i][1] + b24.y;
          o.z = a2[i][2] + b24.z; o.w = a2[i][3] + b24.w;
          store_bf16x4(&C[(size_t)gr * F3H + cp * 128 + col], o);
        }
        a2[i][0] = 0.0f; a2[i][1] = 0.0f; a2[i][2] = 0.0f; a2[i][3] = 0.0f;
      }
    }
  }
}

// ======== fused readout, 32 rows/256 thr, dbuf (R16 exact) ========
__global__ __launch_bounds__(256) __attribute__((amdgpu_waves_per_eu(2, 4)))
void readout_fused(const float* __restrict__ A,
                   const float* __restrict__ W1, const float* __restrict__ b1,
                   const float* __restrict__ W2, const float* __restrict__ b2,
                   float* __restrict__ C, int M) {
  __shared__ float s_a[32][132];
  __shared__ float s_w[2][16][128];
  int i0 = blockIdx.x * 32;
  int tid = threadIdx.x;
  for (int idx = tid; idx < 32 * 128; idx += 256) {
    int r = idx >> 7, k = idx & 127;
    int gr = i0 + r;
    s_a[r][k] = (gr < M) ? A[(size_t)gr * H + k] : 0.0f;
  }
  int mq = tid >> 5, hq = tid & 31;
  int col = 4 * hq;
  int srow = tid >> 5, scol0 = (tid & 31) << 2;
  #pragma unroll
  for (int r = 0; r < 2; r++) {
    int row = srow + r * 8;
    *(float4*)&s_w[0][row][scol0] = *(const float4*)&W1[(size_t)row * H + scol0];
  }
  float acc[4][4] = {};
  for (int p = 0; p < 8; p++) {
    __syncthreads();
    if (p + 1 < 8) {
      #pragma unroll
      for (int r = 0; r < 2; r++) {
        int row = srow + r * 8;
        *(float4*)&s_w[(p + 1) & 1][row][scol0] =
            *(const float4*)&W1[(size_t)((p + 1) * 16 + row) * H + scol0];
      }
    }
    int kp = p * 16;
    #pragma unroll
    for (int kq = 0; kq < 4; kq++) {
      float4 av[4];
      #pragma unroll
      for (int i = 0; i < 4; i++) av[i] = *(const float4*)&s_a[4 * mq + i][kp + 4 * kq];
      #pragma unroll
      for (int k2 = 0; k2 < 4; k2++) {
        float4 w4 = *(const float4*)&s_w[p & 1][4 * kq + k2][4 * hq];
        #pragma unroll
        for (int i = 0; i < 4; i++) {
          float a = ((const float*)&av[i])[k2];
          acc[i][0] += a * w4.x; acc[i][1] += a * w4.y;
          acc[i][2] += a * w4.z; acc[i][3] += a * w4.w;
        }
      }
    }
  }
  float4 b14 = *(const float4*)&b1[col];
  __syncthreads();
  #pragma unroll
  for (int i = 0; i < 4; i++) {
    float4 o;
    o.x = silu_f(acc[i][0] + b14.x); o.y = silu_f(acc[i][1] + b14.y);
    o.z = silu_f(acc[i][2] + b14.z); o.w = silu_f(acc[i][3] + b14.w);
    *(float4*)&s_a[4 * mq + i][col] = o;
  }
  #pragma unroll
  for (int r = 0; r < 2; r++) {
    int row = srow + r * 8;
    *(float4*)&s_w[0][row][scol0] = *(const float4*)&W2[(size_t)row * H + scol0];
  }
  float a2[4][4] = {};
  for (int p = 0; p < 8; p++) {
    __syncthreads();
    if (p + 1 < 8) {
      #pragma unroll
      for (int r = 0; r < 2; r++) {
        int row = srow + r * 8;
        *(float4*)&s_w[(p + 1) & 1][row][scol0] =
            *(const float4*)&W2[(size_t)((p + 1) * 16 + row) * H + scol0];
      }
    }
    int kp = p * 16;
    #pragma unroll
    for (int kq = 0; kq < 4; kq++) {
      float4 av[4];
      #pragma unroll
      for (int i = 0; i < 4; i++) av[i] = *(const float4*)&s_a[4 * mq + i][kp + 4 * kq];
      #pragma unroll
      for (int k2 = 0; k2 < 4; k2++) {
        float4 w4 = *(const float4*)&s_w[p & 1][4 * kq + k2][4 * hq];
        #pragma unroll
        for (int i = 0; i < 4; i++) {
          float a = ((const float*)&av[i])[k2];
          a2[i][0] += a * w4.x; a2[i][1] += a * w4.y;
          a2[i][2] += a * w4.z; a2[i][3] += a * w4.w;
        }
      }
    }
  }
  float4 b24 = *(const float4*)&b2[col];
  #pragma unroll
  for (int i = 0; i < 4; i++) {
    int gr = i0 + 4 * mq + i;
    if (gr < M) {
      float4 o;
      o.x = a2[i][0] + b24.x; o.y = a2[i][1] + b24.y;
      o.z = a2[i][2] + b24.z; o.w = a2[i][3] + b24.w;
      *(float4*)&C[(size_t)gr * H + col] = o;
    }
  }
}

// ---------------- message: bf16 gathers; fp32 state; writes nvB + nvmsg16 + A2 ns-half ----------------
template<bool HASNV>
__global__ __launch_bounds__(128, 4) void message3(
    const int* __restrict__ srcs, const int* __restrict__ rowstart,
    const int* __restrict__ cnt, const float* __restrict__ geo,
    const float* __restrict__ Wf, const float* __restrict__ bfb,
    const bf16* __restrict__ so, const bf16* __restrict__ nvb16,
    const float* __restrict__ nvA,
    float* __restrict__ ns, float* __restrict__ nvB,
    bf16* __restrict__ nvmsg16, bf16* __restrict__ A2, int N) {
  int i = blockIdx.x;
  int h = threadIdx.x;

  float wf0[E_RBF], wf1[E_RBF], wf2[E_RBF];
  #pragma unroll
  for (int k = 0; k < E_RBF; k++) {
    wf0[k] = Wf[k * F3H + h];
    wf1[k] = Wf[k * F3H + H + h];
    wf2[k] = Wf[k * F3H + 2 * H + h];
  }
  float bb0 = bfb[h], bb1 = bfb[H + h], bb2 = bfb[2 * H + h];

  float accs = 0.0f, a0 = 0.0f, a1 = 0.0f, a2 = 0.0f;
  int jlo = rowstart[i], jhi = jlo + cnt[i];
  for (int j = jlo; j < jhi; j++) {
    int src = srcs[j];
    const float* g = geo + (size_t)j * 24;
    float gg[24];
    #pragma unroll
    for (int q = 0; q < 6; q++) *(float4*)&gg[4 * q] = *(const float4*)&g[4 * q];

    float fc = gg[23];
    float f0 = bb0 * fc, f1 = bb1 * fc, f2 = bb2 * fc;
    #pragma unroll
    for (int k = 0; k < E_RBF; k++) {
      float rk = gg[k];
      f0 += rk * wf0[k];
      f1 += rk * wf1[k];
      f2 += rk * wf2[k];
    }
    float u0 = gg[20], u1 = gg[21], u2 = gg[22];

    const bf16* sop = so + (size_t)src * F3H;
    float gsv = f0 * b2f(sop[h]);
    float gev = f1 * b2f(sop[H + h]);
    accs += f2 * b2f(sop[2 * H + h]);

    if (HASNV) {
      const bf16* nvp = nvb16 + (size_t)src * F3H;
      a0 += b2f(nvp[h])         * gsv + gev * u0;
      a1 += b2f(nvp[H + h])     * gsv + gev * u1;
      a2 += b2f(nvp[2 * H + h]) * gsv + gev * u2;
    } else {
      a0 += gev * u0;
      a1 += gev * u1;
      a2 += gev * u2;
    }
  }

  float ns_new = ns[(size_t)i * H + h] + accs;
  ns[(size_t)i * H + h] = ns_new;
  A2[(size_t)i * 256 + 128 + h] = __float2bfloat16(ns_new);
  float o0, o1, o2;
  if (HASNV) {
    const float* nvi = nvA + (size_t)i * F3H;
    o0 = nvi[h] + a0;
    o1 = nvi[H + h] + a1;
    o2 = nvi[2 * H + h] + a2;
  } else {
    o0 = a0; o1 = a1; o2 = a2;
  }
  nvB[(size_t)i * F3H + h]         = o0;
  nvB[(size_t)i * F3H + H + h]     = o1;
  nvB[(size_t)i * F3H + 2 * H + h] = o2;
  nvmsg16[(size_t)i * F3H + h]         = __float2bfloat16(o0);
  nvmsg16[(size_t)i * F3H + H + h]     = __float2bfloat16(o1);
  nvmsg16[(size_t)i * F3H + 2 * H + h] = __float2bfloat16(o2);
}

extern "C" void kernel_launch(void* const* d_in, const int* in_sizes, int n_in,
                              void* d_out, int out_size, void* d_ws, size_t ws_size,
                              hipStream_t stream) {
  const int*   z     = (const int*)d_in[0];
  const int*   edge  = (const int*)d_in[1];
  const float* ediff = (const float*)d_in[2];
  const float* edist = (const float*)d_in[3];
  const float* embed = (const float*)d_in[4];
  const float* mfw   = (const float*)d_in[5];
  const float* mfb   = (const float*)d_in[6];
  const float* mw1   = (const float*)d_in[7];
  const float* mb1   = (const float*)d_in[8];
  const float* mw2   = (const float*)d_in[9];
  const float* mb2   = (const float*)d_in[10];
  const float* uUw   = (const float*)d_in[11];
  const float* uUb   = (const float*)d_in[12];
  const float* uVw   = (const float*)d_in[13];
  const float* uVb   = (const float*)d_in[14];
  const float* uw1   = (const float*)d_in[15];
  const float* ub1   = (const float*)d_in[16];
  const float* uw2   = (const float*)d_in[17];
  const float* ub2   = (const float*)d_in[18];
  const float* rw1   = (const float*)d_in[19];
  const float* rb1   = (const float*)d_in[20];
  const float* rw2   = (const float*)d_in[21];
  const float* rb2   = (const float*)d_in[22];

  const int N  = in_sizes[0];   // 10000
  const int nE = in_sizes[3];   // 160000

  float* ws = (float*)d_ws;
  size_t off = 0;
  float* ns      = ws + off; off += (size_t)N * H;
  float* nvA     = ws + off; off += (size_t)N * F3H;
  float* nvB     = ws + off; off += (size_t)N * F3H;
  float* Vv      = ws + off; off += (size_t)N * F3H;
  float* geo     = ws + off; off += (size_t)nE * 24;
  bf16* so       = (bf16*)(ws + off); off += (size_t)N * F3H / 2;
  bf16* nvb16    = (bf16*)(ws + off); off += (size_t)N * F3H / 2;
  bf16* nvmsg16  = (bf16*)(ws + off); off += (size_t)N * F3H / 2;
  bf16* A2       = (bf16*)(ws + off); off += (size_t)N * 128;       // N*256 bf16
  bf16* m1buf    = (bf16*)(ws + off); off += (size_t)N * 64;        // N*128 bf16
  bf16* wpack    = (bf16*)(ws + off); off += 3 * 2 * 16384 / 2;     // UV
  bf16* wp_m1    = (bf16*)(ws + off); off += 3 * 256 * 128 / 2;
  bf16* wp_m2    = (bf16*)(ws + off); off += 3 * 128 * 384 / 2;
  int* srcs     = (int*)(ws + off); off += nE;
  int* cnt      = (int*)(ws + off); off += N;
  int* rowstart = (int*)(ws + off); off += N;
  int* cur      = (int*)(ws + off); off += N;
  int* elist    = (int*)(ws + off); off += nE;

  const int tilesN = (N + 31) / 32;            // 313
  const int uvBlks = (3 * N + 63) / 64;        // 469

  (void)hipMemsetAsync(cnt, 0, (size_t)N * sizeof(int), stream);
  csr_hist<<<(nE + 255) / 256, 256, 0, stream>>>(edge, cnt, nE);
  csr_scan<<<1, 256, 0, stream>>>(cnt, rowstart, cur, N);
  csr_fill<<<(nE + 255) / 256, 256, 0, stream>>>(edge, cur, elist, nE);
  edge_pack<<<(nE + 255) / 256, 256, 0, stream>>>(elist, edge, edist, ediff, srcs, geo, nE);
  pack_w<<<48, 256, 0, stream>>>(uUw, uVw, wpack);
  pack_b<<<48, 256, 0, stream>>>(uw1, wp_m1, 256, 128, 3);
  pack_b<<<72, 256, 0, stream>>>(uw2, wp_m2, 128, 384, 3);

  node_init<<<N, H, 0, stream>>>(z, embed, ns, N);

  float* nv_cur = nvA;
  float* nv_nxt = nvB;
  for (int l = 0; l < NLAYER; l++) {
    scalar_mlp_fused<<<tilesN, 256, 0, stream>>>(
        ns, mw1 + (size_t)l * H * H, mb1 + (size_t)l * H,
        mw2 + (size_t)l * H * F3H, mb2 + (size_t)l * F3H, so, N);

    if (l == 0)
      message3<false><<<N, H, 0, stream>>>(srcs, rowstart, cnt, geo,
                                           mfw + (size_t)l * E_RBF * F3H, mfb + (size_t)l * F3H,
                                           so, nvb16, nv_cur, ns, nv_nxt, nvmsg16, A2, N);
    else
      message3<true><<<N, H, 0, stream>>>(srcs, rowstart, cnt, geo,
                                          mfw + (size_t)l * E_RBF * F3H, mfb + (size_t)l * F3H,
                                          so, nvb16, nv_cur, ns, nv_nxt, nvmsg16, A2, N);

    float* Uv = nv_cur;  // dead after message3 — reuse as Uv scratch
    gemm_uv_mfma<<<uvBlks, 256, 0, stream>>>(
        nvmsg16, wpack + (size_t)l * 2 * 16384,
        uUb + (size_t)l * H, uVb + (size_t)l * H,
        Uv, Vv, 3 * N);

    vnorm_a2<<<(N * H + 255) / 256, 256, 0, stream>>>(Vv, A2, N);
    gemm_m1_mfma<<<tilesN, 256, 0, stream>>>(
        A2, wp_m1 + (size_t)l * 256 * 128, ub1 + (size_t)l * H, m1buf, N);
    gemm_mo_ep<<<tilesN, 256, 0, stream>>>(
        m1buf, wp_m2 + (size_t)l * 128 * 384, ub2 + (size_t)l * F3H,
        ns, nv_nxt, nvb16, Uv, Vv, N);

    float* t = nv_cur; nv_cur = nv_nxt; nv_nxt = t;
  }

  readout_fused<<<tilesN, 256, 0, stream>>>(ns, rw1, rb1, rw2, rb2, (float*)d_out, N);
}

// Round 20
// 558.616 us; speedup vs baseline: 2.1566x; 1.1405x over previous
//
#include <hip/hip_runtime.h>
#include <hip/hip_bf16.h>

typedef __hip_bfloat16 bf16;
typedef __attribute__((ext_vector_type(8))) short bf16x8;
typedef __attribute__((ext_vector_type(4))) float f32x4;

#define H 128
#define F3H 384
#define E_RBF 20
#define NLAYER 3

__device__ __forceinline__ float silu_f(float x) { return x / (1.0f + __expf(-x)); }
__device__ __forceinline__ float b2f(bf16 x) { return __bfloat162float(x); }

constexpr float PI_F = 3.14159265358979323846f;
constexpr float CUT = 5.0f;

// ---------------- CSR build ----------------
__global__ __launch_bounds__(256) void csr_hist(
    const int* __restrict__ edge, int* __restrict__ cnt, int nE) {
  int e = blockIdx.x * blockDim.x + threadIdx.x;
  if (e < nE) atomicAdd(&cnt[edge[2 * e]], 1);
}

__global__ __launch_bounds__(256) void csr_scan(
    const int* __restrict__ cnt, int* __restrict__ rowstart, int* __restrict__ cur, int N) {
  __shared__ int part[256];
  int t = threadIdx.x;
  int chunk = (N + 255) / 256;
  int lo = t * chunk; if (lo > N) lo = N;
  int hi = lo + chunk; if (hi > N) hi = N;
  int s = 0;
  for (int i = lo; i < hi; i++) s += cnt[i];
  part[t] = s;
  __syncthreads();
  if (t == 0) {
    int r = 0;
    for (int i = 0; i < 256; i++) { int v = part[i]; part[i] = r; r += v; }
  }
  __syncthreads();
  int r = part[t];
  for (int i = lo; i < hi; i++) { rowstart[i] = r; cur[i] = r; r += cnt[i]; }
}

__global__ __launch_bounds__(256) void csr_fill(
    const int* __restrict__ edge, int* __restrict__ cur, int* __restrict__ elist, int nE) {
  int e = blockIdx.x * blockDim.x + threadIdx.x;
  if (e < nE) {
    int d = edge[2 * e];
    int p = atomicAdd(&cur[d], 1);
    elist[p] = e;
  }
}

// ---------------- edge geometry pack ----------------
__global__ __launch_bounds__(256) void edge_pack(
    const int* __restrict__ elist, const int* __restrict__ edge,
    const float* __restrict__ edist, const float* __restrict__ ediff,
    int* __restrict__ srcs, float* __restrict__ geo, int nE) {
  int j = blockIdx.x * blockDim.x + threadIdx.x;
  if (j >= nE) return;
  int e = elist[j];
  srcs[j] = edge[2 * e + 1];
  float d = edist[e];
  float inv = 1.0f / d;
  float th = d * (PI_F / CUT);
  float s1 = sinf(th), c1 = cosf(th);
  float fc = (d < CUT) ? 0.5f * (c1 + 1.0f) : 0.0f;
  float* g = geo + (size_t)j * 24;
  float twoc = 2.0f * c1;
  float skp = 0.0f, sk = s1;
  #pragma unroll
  for (int k = 0; k < E_RBF; k++) {
    g[k] = sk * inv * fc;
    float nx = twoc * sk - skp;
    skp = sk; sk = nx;
  }
  g[20] = ediff[3 * (size_t)e] * inv;
  g[21] = ediff[3 * (size_t)e + 1] * inv;
  g[22] = ediff[3 * (size_t)e + 2] * inv;
  g[23] = fc;
}

// ---------------- node init (fp32 + bf16 shadow) ----------------
__global__ __launch_bounds__(H) void node_init(
    const int* __restrict__ z, const float* __restrict__ embed,
    float* __restrict__ ns, bf16* __restrict__ ns16, int N) {
  int i = blockIdx.x;
  int h = threadIdx.x;
  float v = embed[(size_t)z[i] * H + h];
  ns[(size_t)i * H + h] = v;
  ns16[(size_t)i * H + h] = __float2bfloat16(v);
}

// ---------------- pack U/V weights into MFMA B-fragment layout ----------------
__global__ __launch_bounds__(256) void pack_w(
    const float* __restrict__ Wu, const float* __restrict__ Wv,
    bf16* __restrict__ wp) {
  int t = blockIdx.x * blockDim.x + threadIdx.x;   // 12288 total
  if (t >= 3 * 2 * 4 * 8 * 64) return;
  int lane = t & 63;
  int c    = (t >> 6) & 7;
  int kb   = (t >> 9) & 3;
  int mat  = (t >> 11) & 1;
  int l    = t >> 12;
  const float* src = (mat ? Wv : Wu) + (size_t)l * H * H;
  bf16* dst = wp + ((size_t)(l * 2 + mat) * 16384) + (((kb * 8 + c) * 64 + lane) * 8);
  int quad = lane >> 4;
  int n = c * 16 + (lane & 15);
  #pragma unroll
  for (int j = 0; j < 8; j++) {
    int k = kb * 32 + quad * 8 + j;
    dst[j] = __float2bfloat16(src[(size_t)k * H + n]);
  }
}

// ---------------- generic B-fragment packer ----------------
__global__ __launch_bounds__(256) void pack_b(
    const float* __restrict__ src, bf16* __restrict__ dst,
    int K, int ncols, int L) {
  int kblocks = K >> 5, ncols16 = ncols >> 4;
  int total = L * kblocks * ncols16 * 64;
  int t = blockIdx.x * blockDim.x + threadIdx.x;
  if (t >= total) return;
  int lane = t & 63;
  int idx = t >> 6;
  int c = idx % ncols16; idx /= ncols16;
  int kb = idx % kblocks; idx /= kblocks;
  int l = idx;
  const float* s = src + (size_t)l * K * ncols;
  bf16* d = dst + (size_t)l * K * ncols + (((kb * ncols16 + c) * 64 + lane) * 8);
  int quad = lane >> 4;
  int n = c * 16 + (lane & 15);
  #pragma unroll
  for (int j = 0; j < 8; j++) {
    int k = kb * 32 + quad * 8 + j;
    d[j] = __float2bfloat16(s[(size_t)k * ncols + n]);
  }
}

// ---------------- MFMA dual GEMM: Uv/Vv ----------------
__global__ __launch_bounds__(256) void gemm_uv_mfma(
    const bf16* __restrict__ A, const bf16* __restrict__ Wp,
    const float* __restrict__ bu, const float* __restrict__ bv,
    float* __restrict__ Cu, float* __restrict__ Cv, int M) {
  int wave = threadIdx.x >> 6;
  int lane = threadIdx.x & 63;
  int r0 = blockIdx.x * 64 + wave * 16;
  int quad = lane >> 4;
  int nn = lane & 15;
  int arow = r0 + nn;
  if (arow >= M) arow = M - 1;
  f32x4 accu[8] = {};
  f32x4 accv[8] = {};
  for (int kb = 0; kb < 4; kb++) {
    bf16x8 af = *(const bf16x8*)&A[(size_t)arow * H + kb * 32 + quad * 8];
    #pragma unroll
    for (int c = 0; c < 8; c++) {
      bf16x8 bfu = *(const bf16x8*)&Wp[(((kb * 8 + c) * 64) + lane) * 8];
      bf16x8 bfv = *(const bf16x8*)&Wp[16384 + (((kb * 8 + c) * 64) + lane) * 8];
      accu[c] = __builtin_amdgcn_mfma_f32_16x16x32_bf16(af, bfu, accu[c], 0, 0, 0);
      accv[c] = __builtin_amdgcn_mfma_f32_16x16x32_bf16(af, bfv, accv[c], 0, 0, 0);
    }
  }
  #pragma unroll
  for (int c = 0; c < 8; c++) {
    int n = c * 16 + nn;
    float bub = bu[n], bvb = bv[n];
    #pragma unroll
    for (int r = 0; r < 4; r++) {
      int row = r0 + quad * 4 + r;
      if (row < M) {
        Cu[(size_t)row * H + n] = accu[c][r] + bub;
        Cv[(size_t)row * H + n] = accv[c][r] + bvb;
      }
    }
  }
}

// ---------------- vnorm -> A2[:,0:128] bf16 ----------------
__global__ __launch_bounds__(256) void vnorm_a2(
    const float* __restrict__ Vv, bf16* __restrict__ A2, int N) {
  int t = blockIdx.x * blockDim.x + threadIdx.x;
  if (t >= N * H) return;
  int i = t >> 7, h = t & 127;
  float v0 = Vv[(size_t)(3 * i + 0) * H + h];
  float v1 = Vv[(size_t)(3 * i + 1) * H + h];
  float v2 = Vv[(size_t)(3 * i + 2) * H + h];
  A2[(size_t)i * 256 + h] = __float2bfloat16(sqrtf(v0 * v0 + v1 * v1 + v2 * v2));
}

// ---------------- generic MFMA stage-1: out = silu(A@W+b) -> bf16, 128 cols ----------------
// KB = K/32; A row-stride = K. block 256 = 4 waves (rowg x colhalf).
template<int KB>
__global__ __launch_bounds__(256) void gemm_silu_mfma(
    const bf16* __restrict__ A, const bf16* __restrict__ Wp,
    const float* __restrict__ bias, bf16* __restrict__ out, int M) {
  int wave = threadIdx.x >> 6, lane = threadIdx.x & 63;
  int rowg = wave >> 1, ch = wave & 1;
  int r0 = blockIdx.x * 32 + rowg * 16;
  int quad = lane >> 4, nn = lane & 15;
  int arow = r0 + nn; if (arow >= M) arow = M - 1;
  f32x4 acc[4] = {};
  for (int kb = 0; kb < KB; kb++) {
    bf16x8 af = *(const bf16x8*)&A[(size_t)arow * (KB * 32) + kb * 32 + quad * 8];
    #pragma unroll
    for (int c = 0; c < 4; c++) {
      int cg = ch * 4 + c;
      bf16x8 bw = *(const bf16x8*)&Wp[(((kb * 8 + cg) * 64) + lane) * 8];
      acc[c] = __builtin_amdgcn_mfma_f32_16x16x32_bf16(af, bw, acc[c], 0, 0, 0);
    }
  }
  #pragma unroll
  for (int c = 0; c < 4; c++) {
    int n = (ch * 4 + c) * 16 + nn;
    float bb = bias[n];
    #pragma unroll
    for (int r = 0; r < 4; r++) {
      int row = r0 + quad * 4 + r;
      if (row < M) out[(size_t)row * H + n] = __float2bfloat16(silu_f(acc[c][r] + bb));
    }
  }
}

// ---------------- MFMA stage-2, 384 cols -> bf16 (scalar-MLP "so") ----------------
__global__ __launch_bounds__(256) void gemm_so_mfma(
    const bf16* __restrict__ m1, const bf16* __restrict__ Wp,
    const float* __restrict__ b2, bf16* __restrict__ so, int M) {
  int wave = threadIdx.x >> 6, lane = threadIdx.x & 63;
  int rowg = wave >> 1, ch = wave & 1;
  int r0 = blockIdx.x * 32 + rowg * 16;
  int quad = lane >> 4, nn = lane & 15;
  int arow = r0 + nn; if (arow >= M) arow = M - 1;
  f32x4 a0[4] = {}, a1[4] = {}, a2[4] = {};
  for (int kb = 0; kb < 4; kb++) {
    bf16x8 af = *(const bf16x8*)&m1[(size_t)arow * H + kb * 32 + quad * 8];
    #pragma unroll
    for (int c = 0; c < 4; c++) {
      int cg = ch * 4 + c;
      bf16x8 b0 = *(const bf16x8*)&Wp[(((kb * 24 + cg) * 64) + lane) * 8];
      bf16x8 b1v = *(const bf16x8*)&Wp[(((kb * 24 + cg + 8) * 64) + lane) * 8];
      bf16x8 b2v = *(const bf16x8*)&Wp[(((kb * 24 + cg + 16) * 64) + lane) * 8];
      a0[c] = __builtin_amdgcn_mfma_f32_16x16x32_bf16(af, b0, a0[c], 0, 0, 0);
      a1[c] = __builtin_amdgcn_mfma_f32_16x16x32_bf16(af, b1v, a1[c], 0, 0, 0);
      a2[c] = __builtin_amdgcn_mfma_f32_16x16x32_bf16(af, b2v, a2[c], 0, 0, 0);
    }
  }
  #pragma unroll
  for (int c = 0; c < 4; c++) {
    int n = (ch * 4 + c) * 16 + nn;
    float bb0 = b2[n], bb1 = b2[H + n], bb2 = b2[2 * H + n];
    #pragma unroll
    for (int r = 0; r < 4; r++) {
      int row = r0 + quad * 4 + r;
      if (row < M) {
        so[(size_t)row * F3H + n]           = __float2bfloat16(a0[c][r] + bb0);
        so[(size_t)row * F3H + H + n]       = __float2bfloat16(a1[c][r] + bb1);
        so[(size_t)row * F3H + 2 * H + n]   = __float2bfloat16(a2[c][r] + bb2);
      }
    }
  }
}

// ---------------- MFMA stage-2, 128 cols -> fp32 (readout) ----------------
__global__ __launch_bounds__(256) void gemm_ro2_mfma(
    const bf16* __restrict__ m1, const bf16* __restrict__ Wp,
    const float* __restrict__ b2, float* __restrict__ out, int M) {
  int wave = threadIdx.x >> 6, lane = threadIdx.x & 63;
  int rowg = wave >> 1, ch = wave & 1;
  int r0 = blockIdx.x * 32 + rowg * 16;
  int quad = lane >> 4, nn = lane & 15;
  int arow = r0 + nn; if (arow >= M) arow = M - 1;
  f32x4 acc[4] = {};
  for (int kb = 0; kb < 4; kb++) {
    bf16x8 af = *(const bf16x8*)&m1[(size_t)arow * H + kb * 32 + quad * 8];
    #pragma unroll
    for (int c = 0; c < 4; c++) {
      int cg = ch * 4 + c;
      bf16x8 bw = *(const bf16x8*)&Wp[(((kb * 8 + cg) * 64) + lane) * 8];
      acc[c] = __builtin_amdgcn_mfma_f32_16x16x32_bf16(af, bw, acc[c], 0, 0, 0);
    }
  }
  #pragma unroll
  for (int c = 0; c < 4; c++) {
    int n = (ch * 4 + c) * 16 + nn;
    float bb = b2[n];
    #pragma unroll
    for (int r = 0; r < 4; r++) {
      int row = r0 + quad * 4 + r;
      if (row < M) out[(size_t)row * H + n] = acc[c][r] + bb;
    }
  }
}

// ---------------- MFMA update-MLP stage 2 + gating epilogue (+ns16) ----------------
__global__ __launch_bounds__(256) void gemm_mo_ep(
    const bf16* __restrict__ m1, const bf16* __restrict__ Wp,
    const float* __restrict__ b2,
    float* __restrict__ ns, bf16* __restrict__ ns16,
    float* __restrict__ nv, bf16* __restrict__ nvb16,
    const float* __restrict__ Uv, const float* __restrict__ Vv, int M) {
  int wave = threadIdx.x >> 6, lane = threadIdx.x & 63;
  int rowg = wave >> 1, ch = wave & 1;
  int r0 = blockIdx.x * 32 + rowg * 16;
  int quad = lane >> 4, nn = lane & 15;
  int arow = r0 + nn; if (arow >= M) arow = M - 1;
  f32x4 aav[4] = {}, aas[4] = {}, asz[4] = {};
  for (int kb = 0; kb < 4; kb++) {
    bf16x8 af = *(const bf16x8*)&m1[(size_t)arow * H + kb * 32 + quad * 8];
    #pragma unroll
    for (int c = 0; c < 4; c++) {
      int cg = ch * 4 + c;
      bf16x8 b0 = *(const bf16x8*)&Wp[(((kb * 24 + cg) * 64) + lane) * 8];
      bf16x8 b1v = *(const bf16x8*)&Wp[(((kb * 24 + cg + 8) * 64) + lane) * 8];
      bf16x8 b2v = *(const bf16x8*)&Wp[(((kb * 24 + cg + 16) * 64) + lane) * 8];
      aav[c] = __builtin_amdgcn_mfma_f32_16x16x32_bf16(af, b0, aav[c], 0, 0, 0);
      aas[c] = __builtin_amdgcn_mfma_f32_16x16x32_bf16(af, b1v, aas[c], 0, 0, 0);
      asz[c] = __builtin_amdgcn_mfma_f32_16x16x32_bf16(af, b2v, asz[c], 0, 0, 0);
    }
  }
  #pragma unroll
  for (int c = 0; c < 4; c++) {
    int n = (ch * 4 + c) * 16 + nn;
    float bav = b2[n], bas = b2[H + n], bss = b2[2 * H + n];
    #pragma unroll
    for (int r = 0; r < 4; r++) {
      int row = r0 + quad * 4 + r;
      if (row < M) {
        float avv = aav[c][r] + bav;
        float asv = aas[c][r] + bas;
        float ass = asz[c][r] + bss;
        float u0 = Uv[(size_t)(3 * row + 0) * H + n];
        float u1 = Uv[(size_t)(3 * row + 1) * H + n];
        float u2 = Uv[(size_t)(3 * row + 2) * H + n];
        float v0 = Vv[(size_t)(3 * row + 0) * H + n];
        float v1 = Vv[(size_t)(3 * row + 1) * H + n];
        float v2 = Vv[(size_t)(3 * row + 2) * H + n];
        float dot = u0 * v0 + u1 * v1 + u2 * v2;
        float ns_new = ns[(size_t)row * H + n] + asv * dot + ass;
        ns[(size_t)row * H + n] = ns_new;
        ns16[(size_t)row * H + n] = __float2bfloat16(ns_new);
        float n0 = nv[(size_t)(3 * row + 0) * H + n] + avv * u0;
        float n1 = nv[(size_t)(3 * row + 1) * H + n] + avv * u1;
        float n2 = nv[(size_t)(3 * row + 2) * H + n] + avv * u2;
        nv[(size_t)(3 * row + 0) * H + n] = n0;
        nv[(size_t)(3 * row + 1) * H + n] = n1;
        nv[(size_t)(3 * row + 2) * H + n] = n2;
        nvb16[(size_t)(3 * row + 0) * H + n] = __float2bfloat16(n0);
        nvb16[(size_t)(3 * row + 1) * H + n] = __float2bfloat16(n1);
        nvb16[(size_t)(3 * row + 2) * H + n] = __float2bfloat16(n2);
      }
    }
  }
}

// ---------------- message: bf16 gathers; fp32 state; writes nvB + nvmsg16 + A2 ns-half ----------------
template<bool HASNV>
__global__ __launch_bounds__(128, 4) void message3(
    const int* __restrict__ srcs, const int* __restrict__ rowstart,
    const int* __restrict__ cnt, const float* __restrict__ geo,
    const float* __restrict__ Wf, const float* __restrict__ bfb,
    const bf16* __restrict__ so, const bf16* __restrict__ nvb16,
    const float* __restrict__ nvA,
    float* __restrict__ ns, float* __restrict__ nvB,
    bf16* __restrict__ nvmsg16, bf16* __restrict__ A2, int N) {
  int i = blockIdx.x;
  int h = threadIdx.x;

  float wf0[E_RBF], wf1[E_RBF], wf2[E_RBF];
  #pragma unroll
  for (int k = 0; k < E_RBF; k++) {
    wf0[k] = Wf[k * F3H + h];
    wf1[k] = Wf[k * F3H + H + h];
    wf2[k] = Wf[k * F3H + 2 * H + h];
  }
  float bb0 = bfb[h], bb1 = bfb[H + h], bb2 = bfb[2 * H + h];

  float accs = 0.0f, a0 = 0.0f, a1 = 0.0f, a2 = 0.0f;
  int jlo = rowstart[i], jhi = jlo + cnt[i];
  for (int j = jlo; j < jhi; j++) {
    int src = srcs[j];
    const float* g = geo + (size_t)j * 24;
    float gg[24];
    #pragma unroll
    for (int q = 0; q < 6; q++) *(float4*)&gg[4 * q] = *(const float4*)&g[4 * q];

    float fc = gg[23];
    float f0 = bb0 * fc, f1 = bb1 * fc, f2 = bb2 * fc;
    #pragma unroll
    for (int k = 0; k < E_RBF; k++) {
      float rk = gg[k];
      f0 += rk * wf0[k];
      f1 += rk * wf1[k];
      f2 += rk * wf2[k];
    }
    float u0 = gg[20], u1 = gg[21], u2 = gg[22];

    const bf16* sop = so + (size_t)src * F3H;
    float gsv = f0 * b2f(sop[h]);
    float gev = f1 * b2f(sop[H + h]);
    accs += f2 * b2f(sop[2 * H + h]);

    if (HASNV) {
      const bf16* nvp = nvb16 + (size_t)src * F3H;
      a0 += b2f(nvp[h])         * gsv + gev * u0;
      a1 += b2f(nvp[H + h])     * gsv + gev * u1;
      a2 += b2f(nvp[2 * H + h]) * gsv + gev * u2;
    } else {
      a0 += gev * u0;
      a1 += gev * u1;
      a2 += gev * u2;
    }
  }

  float ns_new = ns[(size_t)i * H + h] + accs;
  ns[(size_t)i * H + h] = ns_new;
  A2[(size_t)i * 256 + 128 + h] = __float2bfloat16(ns_new);
  float o0, o1, o2;
  if (HASNV) {
    const float* nvi = nvA + (size_t)i * F3H;
    o0 = nvi[h] + a0;
    o1 = nvi[H + h] + a1;
    o2 = nvi[2 * H + h] + a2;
  } else {
    o0 = a0; o1 = a1; o2 = a2;
  }
  nvB[(size_t)i * F3H + h]         = o0;
  nvB[(size_t)i * F3H + H + h]     = o1;
  nvB[(size_t)i * F3H + 2 * H + h] = o2;
  nvmsg16[(size_t)i * F3H + h]         = __float2bfloat16(o0);
  nvmsg16[(size_t)i * F3H + H + h]     = __float2bfloat16(o1);
  nvmsg16[(size_t)i * F3H + 2 * H + h] = __float2bfloat16(o2);
}

extern "C" void kernel_launch(void* const* d_in, const int* in_sizes, int n_in,
                              void* d_out, int out_size, void* d_ws, size_t ws_size,
                              hipStream_t stream) {
  const int*   z     = (const int*)d_in[0];
  const int*   edge  = (const int*)d_in[1];
  const float* ediff = (const float*)d_in[2];
  const float* edist = (const float*)d_in[3];
  const float* embed = (const float*)d_in[4];
  const float* mfw   = (const float*)d_in[5];
  const float* mfb   = (const float*)d_in[6];
  const float* mw1   = (const float*)d_in[7];
  const float* mb1   = (const float*)d_in[8];
  const float* mw2   = (const float*)d_in[9];
  const float* mb2   = (const float*)d_in[10];
  const float* uUw   = (const float*)d_in[11];
  const float* uUb   = (const float*)d_in[12];
  const float* uVw   = (const float*)d_in[13];
  const float* uVb   = (const float*)d_in[14];
  const float* uw1   = (const float*)d_in[15];
  const float* ub1   = (const float*)d_in[16];
  const float* uw2   = (const float*)d_in[17];
  const float* ub2   = (const float*)d_in[18];
  const float* rw1   = (const float*)d_in[19];
  const float* rb1   = (const float*)d_in[20];
  const float* rw2   = (const float*)d_in[21];
  const float* rb2   = (const float*)d_in[22];

  const int N  = in_sizes[0];   // 10000
  const int nE = in_sizes[3];   // 160000

  float* ws = (float*)d_ws;
  size_t off = 0;
  float* ns      = ws + off; off += (size_t)N * H;
  float* nvA     = ws + off; off += (size_t)N * F3H;
  float* nvB     = ws + off; off += (size_t)N * F3H;
  float* Vv      = ws + off; off += (size_t)N * F3H;
  float* geo     = ws + off; off += (size_t)nE * 24;
  bf16* so       = (bf16*)(ws + off); off += (size_t)N * F3H / 2;
  bf16* nvb16    = (bf16*)(ws + off); off += (size_t)N * F3H / 2;
  bf16* nvmsg16  = (bf16*)(ws + off); off += (size_t)N * F3H / 2;
  bf16* A2       = (bf16*)(ws + off); off += (size_t)N * 128;       // N*256 bf16
  bf16* m1buf    = (bf16*)(ws + off); off += (size_t)N * 64;        // N*128 bf16
  bf16* ns16     = (bf16*)(ws + off); off += (size_t)N * 64;        // N*128 bf16
  bf16* wpack    = (bf16*)(ws + off); off += 3 * 2 * 16384 / 2;     // UV
  bf16* wp_m1    = (bf16*)(ws + off); off += 3 * 256 * 128 / 2;
  bf16* wp_m2    = (bf16*)(ws + off); off += 3 * 128 * 384 / 2;
  bf16* wp_sm1   = (bf16*)(ws + off); off += 3 * 128 * 128 / 2;
  bf16* wp_sm2   = (bf16*)(ws + off); off += 3 * 128 * 384 / 2;
  bf16* wp_ro1   = (bf16*)(ws + off); off += 128 * 128 / 2;
  bf16* wp_ro2   = (bf16*)(ws + off); off += 128 * 128 / 2;
  int* srcs     = (int*)(ws + off); off += nE;
  int* cnt      = (int*)(ws + off); off += N;
  int* rowstart = (int*)(ws + off); off += N;
  int* cur      = (int*)(ws + off); off += N;
  int* elist    = (int*)(ws + off); off += nE;

  const int tilesN = (N + 31) / 32;            // 313
  const int uvBlks = (3 * N + 63) / 64;        // 469

  (void)hipMemsetAsync(cnt, 0, (size_t)N * sizeof(int), stream);
  csr_hist<<<(nE + 255) / 256, 256, 0, stream>>>(edge, cnt, nE);
  csr_scan<<<1, 256, 0, stream>>>(cnt, rowstart, cur, N);
  csr_fill<<<(nE + 255) / 256, 256, 0, stream>>>(edge, cur, elist, nE);
  edge_pack<<<(nE + 255) / 256, 256, 0, stream>>>(elist, edge, edist, ediff, srcs, geo, nE);
  pack_w<<<48, 256, 0, stream>>>(uUw, uVw, wpack);
  pack_b<<<48, 256, 0, stream>>>(uw1, wp_m1, 256, 128, 3);
  pack_b<<<72, 256, 0, stream>>>(uw2, wp_m2, 128, 384, 3);
  pack_b<<<24, 256, 0, stream>>>(mw1, wp_sm1, 128, 128, 3);
  pack_b<<<72, 256, 0, stream>>>(mw2, wp_sm2, 128, 384, 3);
  pack_b<<<8, 256, 0, stream>>>(rw1, wp_ro1, 128, 128, 1);
  pack_b<<<8, 256, 0, stream>>>(rw2, wp_ro2, 128, 128, 1);

  node_init<<<N, H, 0, stream>>>(z, embed, ns, ns16, N);

  float* nv_cur = nvA;
  float* nv_nxt = nvB;
  for (int l = 0; l < NLAYER; l++) {
    // scalar message MLP (MFMA): m1 = silu(ns16@mw1+mb1); so = m1@mw2+mb2
    gemm_silu_mfma<4><<<tilesN, 256, 0, stream>>>(
        ns16, wp_sm1 + (size_t)l * 128 * 128, mb1 + (size_t)l * H, m1buf, N);
    gemm_so_mfma<<<tilesN, 256, 0, stream>>>(
        m1buf, wp_sm2 + (size_t)l * 128 * 384, mb2 + (size_t)l * F3H, so, N);

    if (l == 0)
      message3<false><<<N, H, 0, stream>>>(srcs, rowstart, cnt, geo,
                                           mfw + (size_t)l * E_RBF * F3H, mfb + (size_t)l * F3H,
                                           so, nvb16, nv_cur, ns, nv_nxt, nvmsg16, A2, N);
    else
      message3<true><<<N, H, 0, stream>>>(srcs, rowstart, cnt, geo,
                                          mfw + (size_t)l * E_RBF * F3H, mfb + (size_t)l * F3H,
                                          so, nvb16, nv_cur, ns, nv_nxt, nvmsg16, A2, N);

    float* Uv = nv_cur;  // dead after message3 — reuse as Uv scratch
    gemm_uv_mfma<<<uvBlks, 256, 0, stream>>>(
        nvmsg16, wpack + (size_t)l * 2 * 16384,
        uUb + (size_t)l * H, uVb + (size_t)l * H,
        Uv, Vv, 3 * N);

    vnorm_a2<<<(N * H + 255) / 256, 256, 0, stream>>>(Vv, A2, N);
    gemm_silu_mfma<8><<<tilesN, 256, 0, stream>>>(
        A2, wp_m1 + (size_t)l * 256 * 128, ub1 + (size_t)l * H, m1buf, N);
    gemm_mo_ep<<<tilesN, 256, 0, stream>>>(
        m1buf, wp_m2 + (size_t)l * 128 * 384, ub2 + (size_t)l * F3H,
        ns, ns16, nv_nxt, nvb16, Uv, Vv, N);

    float* t = nv_cur; nv_cur = nv_nxt; nv_nxt = t;
  }

  gemm_silu_mfma<4><<<tilesN, 256, 0, stream>>>(ns16, wp_ro1, rb1, m1buf, N);
  gemm_ro2_mfma<<<tilesN, 256, 0, stream>>>(m1buf, wp_ro2, rb2, (float*)d_out, N);
}